// Round 5
// baseline (32701.965 us; speedup 1.0000x reference)
//
#include <hip/hip_runtime.h>

typedef unsigned int u32;
typedef unsigned short u16;
typedef __attribute__((ext_vector_type(4))) u32 u32x4;
typedef __attribute__((ext_vector_type(4))) u16 u16x4;
typedef __attribute__((ext_vector_type(8))) short bf16x8;
typedef __attribute__((ext_vector_type(4))) float f32x4;
typedef __attribute__((ext_vector_type(2))) _Float16 h2f;

__device__ __forceinline__ u16 f2bf(float x){
  u32 u = __builtin_bit_cast(u32, x);
  u = (u + 0x7fffu + ((u >> 16) & 1u)) >> 16;
  return (u16)u;
}
__device__ __forceinline__ u16 f2h(float x){
  _Float16 h = (_Float16)x;
  return __builtin_bit_cast(u16, h);
}
__device__ __forceinline__ h2f as_h2(u32 v){ return __builtin_bit_cast(h2f, v); }
__device__ __forceinline__ float sigf(float x){ return 1.0f/(1.0f + __expf(-x)); }
__device__ __forceinline__ float tanh_f(float x){ float e = __expf(2.0f*x); return 1.0f - 2.0f/(e + 1.0f); }

__device__ __forceinline__ float dot2acc(u32 a, u32 b, float acc){
#if __has_builtin(__builtin_amdgcn_fdot2)
  return __builtin_amdgcn_fdot2(as_h2(a), as_h2(b), acc, false);
#else
  h2f ha = as_h2(a), hb = as_h2(b);
  return acc + (float)ha[0]*(float)hb[0] + (float)ha[1]*(float)hb[1];
#endif
}

// ---------------- conversion kernels ----------------

// x (1024 x 50001) f32 -> xb (1024 x 50176) bf16, zero-pad cols [50000,50176)
__global__ void conv_x(const float* __restrict__ x, u16* __restrict__ xb){
  int col4 = (blockIdx.x*256 + threadIdx.x)*4;   // grid (49, 1024)
  int row  = blockIdx.y;
  const float* src = x + (long)row*50001 + col4;
  u16x4 v;
  if (col4 < 50000) { v[0]=f2bf(src[0]); v[1]=f2bf(src[1]); v[2]=f2bf(src[2]); v[3]=f2bf(src[3]); }
  else { v[0]=0; v[1]=0; v[2]=0; v[3]=0; }
  *(u16x4*)(xb + (long)row*50176 + col4) = v;
}

// enc_w1 (512 x 50000) f32 -> w1b (512 x 50176) bf16 padded
__global__ void conv_w1(const float* __restrict__ w, u16* __restrict__ wb){
  int col4 = (blockIdx.x*256 + threadIdx.x)*4;   // grid (49, 512)
  int row  = blockIdx.y;
  const float* src = w + (long)row*50000 + col4;
  u16x4 v;
  if (col4 < 50000) { v[0]=f2bf(src[0]); v[1]=f2bf(src[1]); v[2]=f2bf(src[2]); v[3]=f2bf(src[3]); }
  else { v[0]=0; v[1]=0; v[2]=0; v[3]=0; }
  *(u16x4*)(wb + (long)row*50176 + col4) = v;
}

// enc_w2 (256x512), dec_w1 (512x256), gate W_w stacked -> bf16
__global__ void conv_misc(const float* __restrict__ enc_w2, const float* __restrict__ dec_w1,
                          const float* __restrict__ dw, const float* __restrict__ iw,
                          const float* __restrict__ ow, const float* __restrict__ cw,
                          u16* __restrict__ w2eb, u16* __restrict__ wd1b, u16* __restrict__ wgb){
  int idx = blockIdx.x*256 + threadIdx.x;        // grid 2048
  if (idx < 131072) {
    w2eb[idx] = f2bf(enc_w2[idx]);
  } else if (idx < 262144) {
    int i = idx - 131072;
    wd1b[i] = f2bf(dec_w1[i]);
  } else {
    int i = idx - 262144;                        // 262144 elems: wgb[o][k], o = g*256+e
    int o = i >> 8, k = i & 255;
    int g = o >> 8, e = o & 255;
    const float* W = (g==0) ? dw : (g==1) ? iw : (g==2) ? ow : cw;
    wgb[i] = f2bf(W[e*256 + k]);
  }
}

// combined gate biases: bws[o] = u_b[e] + w_b[e]
__global__ void pack_bias(const float* dub, const float* dwb, const float* iub, const float* iwb,
                          const float* oub, const float* owb, const float* cub, const float* cwb,
                          float* __restrict__ bws){
  int o = blockIdx.x*256 + threadIdx.x;          // grid 4
  int g = o >> 8, e = o & 255;
  float v;
  if      (g==0) v = dub[e] + dwb[e];
  else if (g==1) v = iub[e] + iwb[e];
  else if (g==2) v = oub[e] + owb[e];
  else           v = cub[e] + cwb[e];
  bws[o] = v;
}

// Pack recurrent U matrices for the scan.
// Thread t (of 512): q=t>>2, c=t&3; owns outputs o=q*8+j (j<8), k in [c*64, c*64+64).
// Reg part k-cols [0,48): upack[((j*6+b)*512 + t)*4 + p]  (b=kk2>>2, p=kk2&3, kk2=kk/2)
//   -> each thread's (j,b) quad is 16B contiguous => one dwordx4 load in the scan.
// LDS part k-cols [48,64): utail image (unchanged layout).
__global__ void pack_u(const float* du, const float* iu, const float* ou, const float* cu,
                       u32* __restrict__ upack, u16* __restrict__ utail_img){
  int t = threadIdx.x;                           // 1 block, 512 threads
  int c = t & 3, q = t >> 2;
  for (int j = 0; j < 8; ++j) {
    int o = q*8 + j;
    int g = o >> 8, e = o & 255;
    const float* U = (g==0) ? du : (g==1) ? iu : (g==2) ? ou : cu;
    const float* row = U + e*256 + c*64;
    for (int kk2 = 0; kk2 < 24; ++kk2) {
      u32 lo = f2h(row[kk2*2]);
      u32 hi = f2h(row[kk2*2+1]);
      upack[(((long)j*6 + (kk2>>2))*512 + t)*4 + (kk2&3)] = lo | (hi << 16);
    }
    for (int kk = 48; kk < 64; ++kk) {
      int s = (kk-48) >> 3, b = (kk-48) & 7;
      utail_img[(size_t)((j*2+s)*512 + t)*8 + b] = f2h(row[kk]);
    }
  }
}

// ---------------- MFMA GEMM: C = A @ B^T, A[M][K] bf16, B[N][K] bf16 ----------------
// EPI: 0 = store f32 partial at Cf + z*1024*ldc (split-K)
//      1 = bias + relu -> bf16 Cb
//      2 = bias -> f32 Cf
//      3 = bias + sigmoid -> f32 Cf with col < nGuard
template<int EPI>
__global__ __launch_bounds__(256)
void gemm_bt(const u16* __restrict__ A, const u16* __restrict__ B,
             const float* __restrict__ bias, float* __restrict__ Cf, u16* __restrict__ Cb,
             int lda, int ldb, int ldc, int kiters, int nGuard){
  __shared__ u16 As[128*32];
  __shared__ u16 Bs[128*32];
  const int tid = threadIdx.x;
  const int l = tid & 63;
  const int w = tid >> 6;
  const int wr = w >> 1, wc = w & 1;             // 2x2 wave grid, 64x64 per wave
  const long kchunk = (long)blockIdx.z * kiters * 32;
  const u16* Ab = A + (long)blockIdx.x*128*lda + kchunk;
  const u16* Bb = B + (long)blockIdx.y*128*ldb + kchunk;
  f32x4 acc[4][4];
#pragma unroll
  for (int m=0;m<4;m++)
#pragma unroll
    for (int n=0;n<4;n++) acc[m][n] = (f32x4){0.f,0.f,0.f,0.f};

  const int lr = l & 15, lk = l >> 4;
  for (int it = 0; it < kiters; ++it) {
    {
      int s = tid;
      int row = s >> 2, kg = s & 3;
      u32x4 va = *(const u32x4*)(Ab + (long)row*lda + (long)it*32 + kg*8);
      u32x4 vb = *(const u32x4*)(Bb + (long)row*ldb + (long)it*32 + kg*8);
      int sw = ((kg + row) & 3) * 8;
      *(u32x4*)&As[row*32 + sw] = va;
      *(u32x4*)&Bs[row*32 + sw] = vb;
      s = tid + 256;
      row = s >> 2; kg = s & 3;
      va = *(const u32x4*)(Ab + (long)row*lda + (long)it*32 + kg*8);
      vb = *(const u32x4*)(Bb + (long)row*ldb + (long)it*32 + kg*8);
      sw = ((kg + row) & 3) * 8;
      *(u32x4*)&As[row*32 + sw] = va;
      *(u32x4*)&Bs[row*32 + sw] = vb;
    }
    __syncthreads();
    bf16x8 af[4], bfr[4];
#pragma unroll
    for (int m=0;m<4;m++) {
      int row = wr*64 + m*16 + lr;
      af[m] = *(const bf16x8*)&As[row*32 + (((lk + row)&3)*8)];
    }
#pragma unroll
    for (int n=0;n<4;n++) {
      int row = wc*64 + n*16 + lr;
      bfr[n] = *(const bf16x8*)&Bs[row*32 + (((lk + row)&3)*8)];
    }
#pragma unroll
    for (int m=0;m<4;m++)
#pragma unroll
      for (int n=0;n<4;n++)
        acc[m][n] = __builtin_amdgcn_mfma_f32_16x16x32_bf16(af[m], bfr[n], acc[m][n], 0, 0, 0);
    __syncthreads();
  }
#pragma unroll
  for (int m=0;m<4;m++) {
#pragma unroll
    for (int n=0;n<4;n++) {
#pragma unroll
      for (int v=0;v<4;v++) {
        int r  = wr*64 + m*16 + lk*4 + v;
        int cn = wc*64 + n*16 + lr;
        long gr = (long)blockIdx.x*128 + r;
        long gc = (long)blockIdx.y*128 + cn;
        float val = acc[m][n][v];
        if (EPI == 0) {
          Cf[((long)blockIdx.z*1024 + gr)*ldc + gc] = val;
        } else if (EPI == 1) {
          float y = val + bias[gc];
          y = y > 0.f ? y : 0.f;
          Cb[gr*ldc + gc] = f2bf(y);
        } else if (EPI == 2) {
          Cf[gr*ldc + gc] = val + bias[gc];
        } else if (EPI == 3) {
          if (gc < nGuard) Cf[gr*ldc + gc] = sigf(val + bias[gc]);
        }
      }
    }
  }
}

// sum split-K partials + bias + relu -> bf16 h1b
__global__ void reduce1(const float* __restrict__ P, const float* __restrict__ b1,
                        u16* __restrict__ h1b){
  int idx = blockIdx.x*256 + threadIdx.x;        // grid 2048 -> 524288 = 1024*512
  float s = b1[idx & 511];
#pragma unroll
  for (int kc = 0; kc < 32; ++kc) s += P[(long)kc*524288 + idx];
  h1b[idx] = f2bf(s > 0.f ? s : 0.f);
}

// ---------------- sequential scan: block 0 of grid; blocks >=1 convert dec_w2 ----------------
// r2-r4 all reported VGPR_Count=128 regardless of occupancy hints -> the ur[192]
// array never became register SSA values (stayed a scratch object; ~400 KB/step
// streamed at ~64 B/cy = the observed ~6800 cy/step). Fix: NO ARRAY. 48 named
// u32x4 variables loaded once, consumed by macro-unrolled fdot2 chains. With
// waves_per_eu(2,2) (LDS already caps at 2 waves/SIMD) the ~240 live values fit
// the 256-VGPR budget.
#define LDU(J,B) u32x4 U##J##_##B = *(const u32x4*)(upack + (((J)*6+(B))*512 + t)*4)
#define ACCJB(J,B) a##J = dot2acc(U##J##_##B[3],hb[3],dot2acc(U##J##_##B[2],hb[2],dot2acc(U##J##_##B[1],hb[1],dot2acc(U##J##_##B[0],hb[0],a##J))))
#define BBLOCK(B) { u32x4 hb = *(const u32x4*)&hlds[c*64 + (B)*8]; \
  ACCJB(0,B); ACCJB(1,B); ACCJB(2,B); ACCJB(3,B); ACCJB(4,B); ACCJB(5,B); ACCJB(6,B); ACCJB(7,B); }
#define TAILJ(J,S) { u32x4 ut = *(const u32x4*)&utail[(size_t)(((J)*2+(S))*512 + t)*8]; \
  a##J = dot2acc(ut[3],hb[3],dot2acc(ut[2],hb[2],dot2acc(ut[1],hb[1],dot2acc(ut[0],hb[0],a##J)))); }
#define TBLOCK(S) { u32x4 hb = *(const u32x4*)&hlds[c*64 + 48 + (S)*8]; \
  TAILJ(0,S); TAILJ(1,S); TAILJ(2,S); TAILJ(3,S); TAILJ(4,S); TAILJ(5,S); TAILJ(6,S); TAILJ(7,S); }

__global__ __launch_bounds__(512) __attribute__((amdgpu_waves_per_eu(2,2)))
void scan_kernel(const u32* __restrict__ upack, const u32x4* __restrict__ utail_img,
                 const float* __restrict__ xw, u16* __restrict__ hsb,
                 const float* __restrict__ dec_w2, u16* __restrict__ w2db){
  __shared__ u16   utail[65536];                 // 131072 B  (static LDS total 135,680 B)
  __shared__ float preact[1024];                 // 4096 B    (index o = g*256+e)
  __shared__ u16   hlds[256];                    // 512 B     (h as f16)

  if (blockIdx.x != 0) {
    // dec_w2 (50000x512) f32 -> w2db (50048x512) bf16, rows >= 50000 zeroed.
    const long total = (50048L*512)/4;           // u16x4 groups
    const long stride = (long)(gridDim.x - 1)*512;
    for (long g2 = (long)(blockIdx.x-1)*512 + threadIdx.x; g2 < total; g2 += stride) {
      long base = g2*4;
      long row = base >> 9;
      u16x4 v;
      if (row < 50000) {
        const float* s = dec_w2 + base;
        v[0]=f2bf(s[0]); v[1]=f2bf(s[1]); v[2]=f2bf(s[2]); v[3]=f2bf(s[3]);
      } else { v[0]=0; v[1]=0; v[2]=0; v[3]=0; }
      *(u16x4*)(w2db + base) = v;
    }
    return;
  }

  const int t = threadIdx.x;
  const int c = t & 3;
  const int q = t >> 2;

  // 48 named U quads (192 u32) -- loaded once, register-resident
  LDU(0,0); LDU(0,1); LDU(0,2); LDU(0,3); LDU(0,4); LDU(0,5);
  LDU(1,0); LDU(1,1); LDU(1,2); LDU(1,3); LDU(1,4); LDU(1,5);
  LDU(2,0); LDU(2,1); LDU(2,2); LDU(2,3); LDU(2,4); LDU(2,5);
  LDU(3,0); LDU(3,1); LDU(3,2); LDU(3,3); LDU(3,4); LDU(3,5);
  LDU(4,0); LDU(4,1); LDU(4,2); LDU(4,3); LDU(4,4); LDU(4,5);
  LDU(5,0); LDU(5,1); LDU(5,2); LDU(5,3); LDU(5,4); LDU(5,5);
  LDU(6,0); LDU(6,1); LDU(6,2); LDU(6,3); LDU(6,4); LDU(6,5);
  LDU(7,0); LDU(7,1); LDU(7,2); LDU(7,3); LDU(7,4); LDU(7,5);

#pragma unroll
  for (int i = 0; i < 16; ++i)
    ((u32x4*)utail)[i*512 + t] = utail_img[i*512 + t];

  u32 hq[25];
#pragma unroll
  for (int i = 0; i < 25; ++i) hq[i] = 0;
  if (t < 256) hlds[t] = 0;
  __syncthreads();
  asm volatile("" ::: "memory");                 // U values must stay live (no re-load)

  for (int st = 0; st < 1024; ++st) {
    float xw0=0.f, xw1=0.f, xw2=0.f, xw3=0.f;
    if (t < 256) {                               // prefetch; consumed after phase A
      xw0 = xw[st*1024 + t];
      xw1 = xw[st*1024 + 256 + t];
      xw2 = xw[st*1024 + 512 + t];
      xw3 = xw[st*1024 + 768 + t];
    }
    // ---- phase A: preact[o] = sum_k h[k]*U[o][k]  (this thread: k in [c*64,c*64+64)) ----
    float a0=0.f,a1=0.f,a2=0.f,a3=0.f,a4=0.f,a5=0.f,a6=0.f,a7=0.f;
    BBLOCK(0); BBLOCK(1); BBLOCK(2); BBLOCK(3); BBLOCK(4); BBLOCK(5);
    TBLOCK(0); TBLOCK(1);
    a0 += __shfl_xor(a0,1); a0 += __shfl_xor(a0,2);
    a1 += __shfl_xor(a1,1); a1 += __shfl_xor(a1,2);
    a2 += __shfl_xor(a2,1); a2 += __shfl_xor(a2,2);
    a3 += __shfl_xor(a3,1); a3 += __shfl_xor(a3,2);
    a4 += __shfl_xor(a4,1); a4 += __shfl_xor(a4,2);
    a5 += __shfl_xor(a5,1); a5 += __shfl_xor(a5,2);
    a6 += __shfl_xor(a6,1); a6 += __shfl_xor(a6,2);
    a7 += __shfl_xor(a7,1); a7 += __shfl_xor(a7,2);
    *(f32x4*)&preact[q*8]     = (f32x4){a0,a1,a2,a3};
    *(f32x4*)&preact[q*8 + 4] = (f32x4){a4,a5,a6,a7};
    __syncthreads();

    // ---- phase B: gates + lag-memory + h update (threads 0..255, e = t) ----
    if (t < 256) {
      float pd = preact[t]       + xw0;
      float pi = preact[256 + t] + xw1;
      float po = preact[512 + t] + xw2;
      float pc = preact[768 + t] + xw3;
      float d  = 0.5f * sigf(pd);
      float gi = sigf(pi);
      float go = sigf(po);
      float ct = tanh_f(pc);
      float cur = gi * ct;
      // mem = sum_k w_k*hist_k ; w_0=1, w_k = w_{k-1}*((d+k-1)/k)  (== exp(gammaln ratio))
      float mem0 = cur, mem1 = 0.0f;
      float wk = 1.0f;
#pragma unroll
      for (int k = 1; k < 50; ++k) {
        wk *= (d + (float)(k-1)) * (1.0f/(float)k);
        u32 pair = hq[(k-1) >> 1];
        float hv = ((k-1) & 1) ? (float)as_h2(pair)[1] : (float)as_h2(pair)[0];
        if (k & 1) mem1 += wk * hv; else mem0 += wk * hv;
      }
      float hnew = go * tanh_f(mem0 + mem1);
#pragma unroll
      for (int i = 24; i >= 1; --i) hq[i] = (hq[i] << 16) | (hq[i-1] >> 16);
      hq[0] = (hq[0] << 16) | (u32)f2h(cur);
      hlds[t] = f2h(hnew);
      hsb[st*256 + t] = f2bf(hnew);
    }
    __syncthreads();
  }
}

// ---------------- launcher ----------------
extern "C" void kernel_launch(void* const* d_in, const int* in_sizes, int n_in,
                              void* d_out, int out_size, void* d_ws, size_t ws_size,
                              hipStream_t stream){
  const float* x      = (const float*)d_in[0];
  const float* enc_w1 = (const float*)d_in[1];
  const float* enc_b1 = (const float*)d_in[2];
  const float* enc_w2 = (const float*)d_in[3];
  const float* enc_b2 = (const float*)d_in[4];
  const float* d_u_w  = (const float*)d_in[5];  const float* d_u_b = (const float*)d_in[6];
  const float* d_w_w  = (const float*)d_in[7];  const float* d_w_b = (const float*)d_in[8];
  const float* i_u_w  = (const float*)d_in[9];  const float* i_u_b = (const float*)d_in[10];
  const float* i_w_w  = (const float*)d_in[11]; const float* i_w_b = (const float*)d_in[12];
  const float* o_u_w  = (const float*)d_in[13]; const float* o_u_b = (const float*)d_in[14];
  const float* o_w_w  = (const float*)d_in[15]; const float* o_w_b = (const float*)d_in[16];
  const float* c_u_w  = (const float*)d_in[17]; const float* c_u_b = (const float*)d_in[18];
  const float* c_w_w  = (const float*)d_in[19]; const float* c_w_b = (const float*)d_in[20];
  const float* dec_w1 = (const float*)d_in[21]; const float* dec_b1 = (const float*)d_in[22];
  const float* dec_w2 = (const float*)d_in[23]; const float* dec_b2 = (const float*)d_in[24];

  char* ws = (char*)d_ws;
  u16*   xb     = (u16*)(ws + 0L);                 // 1024*50176*2
  u16*   w1b    = (u16*)(ws + 102760448L);         // 512*50176*2
  u16*   w2db   = (u16*)(ws + 154140672L);         // 50048*512*2
  u16*   h1b    = (u16*)(ws + 205389824L);         // 1024*512*2
  u16*   e_b    = (u16*)(ws + 206438400L);         // 1024*256*2
  u16*   wgb    = (u16*)(ws + 206962688L);         // 1024*256*2
  u16*   w2eb   = (u16*)(ws + 207486976L);         // 256*512*2
  u16*   wd1b   = (u16*)(ws + 207749120L);         // 512*256*2
  u16*   d1b    = (u16*)(ws + 208011264L);         // 1024*512*2
  u16*   hsb    = (u16*)(ws + 209059840L);         // 1024*256*2
  float* xw     = (float*)(ws + 209584128L);       // 1024*1024*4
  float* bws    = (float*)(ws + 213778432L);       // 1024*4
  u32*   upack  = (u32*)(ws + 213782528L);         // 48*512*4 u32x4 = 393216 B
  u16*   utailI = (u16*)(ws + 214175744L);         // 16*512*16
  float* out    = (float*)d_out;
  float* P      = (float*)d_out;                   // split-K partials reuse d_out

  conv_x   <<<dim3(49,1024), 256, 0, stream>>>(x, xb);
  conv_w1  <<<dim3(49,512),  256, 0, stream>>>(enc_w1, w1b);
  conv_misc<<<2048, 256, 0, stream>>>(enc_w2, dec_w1, d_w_w, i_w_w, o_w_w, c_w_w, w2eb, wd1b, wgb);
  pack_bias<<<4, 256, 0, stream>>>(d_u_b, d_w_b, i_u_b, i_w_b, o_u_b, o_w_b, c_u_b, c_w_b, bws);
  pack_u   <<<1, 512, 0, stream>>>(d_u_w, i_u_w, o_u_w, c_u_w, upack, utailI);

  gemm_bt<0><<<dim3(8,4,32), 256, 0, stream>>>(xb, w1b, nullptr, P, nullptr, 50176, 50176, 512, 49, 0);
  reduce1<<<2048, 256, 0, stream>>>(P, enc_b1, h1b);
  gemm_bt<1><<<dim3(8,2,1), 256, 0, stream>>>(h1b, w2eb, enc_b2, nullptr, e_b, 512, 512, 256, 16, 0);
  gemm_bt<2><<<dim3(8,8,1), 256, 0, stream>>>(e_b, wgb, bws, xw, nullptr, 256, 256, 1024, 8, 0);
  // sequential recurrence (block 0) + dec_w2 bf16 convert (blocks 1..196)
  scan_kernel<<<197, 512, 0, stream>>>(upack, (const u32x4*)utailI, xw, hsb, dec_w2, w2db);
  gemm_bt<1><<<dim3(8,4,1), 256, 0, stream>>>(hsb, wd1b, dec_b1, nullptr, d1b, 256, 256, 512, 8, 0);
  gemm_bt<3><<<dim3(8,391,1), 256, 0, stream>>>(d1b, w2db, dec_b2, out, nullptr, 512, 512, 50000, 16, 50000);
}

// Round 6
// 6657.979 us; speedup vs baseline: 4.9117x; 4.9117x over previous
//
#include <hip/hip_runtime.h>

typedef unsigned int u32;
typedef unsigned short u16;
typedef __attribute__((ext_vector_type(4))) u32 u32x4;
typedef __attribute__((ext_vector_type(4))) u16 u16x4;
typedef __attribute__((ext_vector_type(8))) short bf16x8;
typedef __attribute__((ext_vector_type(4))) float f32x4;
typedef __attribute__((ext_vector_type(2))) _Float16 h2f;

__device__ __forceinline__ u16 f2bf(float x){
  u32 u = __builtin_bit_cast(u32, x);
  u = (u + 0x7fffu + ((u >> 16) & 1u)) >> 16;
  return (u16)u;
}
__device__ __forceinline__ u16 f2h(float x){
  _Float16 h = (_Float16)x;
  return __builtin_bit_cast(u16, h);
}
__device__ __forceinline__ h2f as_h2(u32 v){ return __builtin_bit_cast(h2f, v); }
__device__ __forceinline__ float sigf(float x){ return 1.0f/(1.0f + __expf(-x)); }
__device__ __forceinline__ float tanh_f(float x){ float e = __expf(2.0f*x); return 1.0f - 2.0f/(e + 1.0f); }

__device__ __forceinline__ float dot2acc(u32 a, u32 b, float acc){
#if __has_builtin(__builtin_amdgcn_fdot2)
  return __builtin_amdgcn_fdot2(as_h2(a), as_h2(b), acc, false);
#else
  h2f ha = as_h2(a), hb = as_h2(b);
  return acc + (float)ha[0]*(float)hb[0] + (float)ha[1]*(float)hb[1];
#endif
}

// ---------------- conversion kernels ----------------

// x (1024 x 50001) f32 -> xb (1024 x 50176) bf16, zero-pad cols [50000,50176)
__global__ void conv_x(const float* __restrict__ x, u16* __restrict__ xb){
  int col4 = (blockIdx.x*256 + threadIdx.x)*4;   // grid (49, 1024)
  int row  = blockIdx.y;
  const float* src = x + (long)row*50001 + col4;
  u16x4 v;
  if (col4 < 50000) { v[0]=f2bf(src[0]); v[1]=f2bf(src[1]); v[2]=f2bf(src[2]); v[3]=f2bf(src[3]); }
  else { v[0]=0; v[1]=0; v[2]=0; v[3]=0; }
  *(u16x4*)(xb + (long)row*50176 + col4) = v;
}

// enc_w1 (512 x 50000) f32 -> w1b (512 x 50176) bf16 padded
__global__ void conv_w1(const float* __restrict__ w, u16* __restrict__ wb){
  int col4 = (blockIdx.x*256 + threadIdx.x)*4;   // grid (49, 512)
  int row  = blockIdx.y;
  const float* src = w + (long)row*50000 + col4;
  u16x4 v;
  if (col4 < 50000) { v[0]=f2bf(src[0]); v[1]=f2bf(src[1]); v[2]=f2bf(src[2]); v[3]=f2bf(src[3]); }
  else { v[0]=0; v[1]=0; v[2]=0; v[3]=0; }
  *(u16x4*)(wb + (long)row*50176 + col4) = v;
}

// enc_w2 (256x512), dec_w1 (512x256), gate W_w stacked -> bf16
__global__ void conv_misc(const float* __restrict__ enc_w2, const float* __restrict__ dec_w1,
                          const float* __restrict__ dw, const float* __restrict__ iw,
                          const float* __restrict__ ow, const float* __restrict__ cw,
                          u16* __restrict__ w2eb, u16* __restrict__ wd1b, u16* __restrict__ wgb){
  int idx = blockIdx.x*256 + threadIdx.x;        // grid 2048
  if (idx < 131072) {
    w2eb[idx] = f2bf(enc_w2[idx]);
  } else if (idx < 262144) {
    int i = idx - 131072;
    wd1b[i] = f2bf(dec_w1[i]);
  } else {
    int i = idx - 262144;                        // 262144 elems: wgb[o][k], o = g*256+e
    int o = i >> 8, k = i & 255;
    int g = o >> 8, e = o & 255;
    const float* W = (g==0) ? dw : (g==1) ? iw : (g==2) ? ow : cw;
    wgb[i] = f2bf(W[e*256 + k]);
  }
}

// combined gate biases: bws[o] = u_b[e] + w_b[e]
__global__ void pack_bias(const float* dub, const float* dwb, const float* iub, const float* iwb,
                          const float* oub, const float* owb, const float* cub, const float* cwb,
                          float* __restrict__ bws){
  int o = blockIdx.x*256 + threadIdx.x;          // grid 4
  int g = o >> 8, e = o & 255;
  float v;
  if      (g==0) v = dub[e] + dwb[e];
  else if (g==1) v = iub[e] + iwb[e];
  else if (g==2) v = oub[e] + owb[e];
  else           v = cub[e] + cwb[e];
  bws[o] = v;
}

// Pack recurrent U matrices for the 1024-thread scan.
// Thread t: q=t>>2 owns outputs o=q*4+j (j<4); c=t&3 -> k in [c*64,(c+1)*64).
// Reg part k-cols [0,48): upack[((j*6+b)*1024 + t)*4 + p]  (kk2 = b*4+p, pair kk2 = k {2kk2,2kk2+1})
// LDS part k-cols [48,64): utail_img[((j*2+s)*1024 + t)*8 + b]
__global__ void pack_u(const float* du, const float* iu, const float* ou, const float* cu,
                       u32* __restrict__ upack, u16* __restrict__ utail_img){
  int t = threadIdx.x;                           // 1 block, 1024 threads
  int c = t & 3, q = t >> 2;
  for (int j = 0; j < 4; ++j) {
    int o = q*4 + j;
    int g = o >> 8, e = o & 255;
    const float* U = (g==0) ? du : (g==1) ? iu : (g==2) ? ou : cu;
    const float* row = U + e*256 + c*64;
    for (int kk2 = 0; kk2 < 24; ++kk2) {
      u32 lo = f2h(row[kk2*2]);
      u32 hi = f2h(row[kk2*2+1]);
      upack[(((long)j*6 + (kk2>>2))*1024 + t)*4 + (kk2&3)] = lo | (hi << 16);
    }
    for (int kk = 48; kk < 64; ++kk) {
      int s = (kk-48) >> 3, b = (kk-48) & 7;
      utail_img[(size_t)((j*2+s)*1024 + t)*8 + b] = f2h(row[kk]);
    }
  }
}

// ---------------- MFMA GEMM: C = A @ B^T, A[M][K] bf16, B[N][K] bf16 ----------------
// EPI: 0 = store f32 partial at Cf + z*1024*ldc (split-K)
//      1 = bias + relu -> bf16 Cb
//      2 = bias -> f32 Cf
//      3 = bias + sigmoid -> f32 Cf with col < nGuard
template<int EPI>
__global__ __launch_bounds__(256)
void gemm_bt(const u16* __restrict__ A, const u16* __restrict__ B,
             const float* __restrict__ bias, float* __restrict__ Cf, u16* __restrict__ Cb,
             int lda, int ldb, int ldc, int kiters, int nGuard){
  __shared__ u16 As[128*32];
  __shared__ u16 Bs[128*32];
  const int tid = threadIdx.x;
  const int l = tid & 63;
  const int w = tid >> 6;
  const int wr = w >> 1, wc = w & 1;             // 2x2 wave grid, 64x64 per wave
  const long kchunk = (long)blockIdx.z * kiters * 32;
  const u16* Ab = A + (long)blockIdx.x*128*lda + kchunk;
  const u16* Bb = B + (long)blockIdx.y*128*ldb + kchunk;
  f32x4 acc[4][4];
#pragma unroll
  for (int m=0;m<4;m++)
#pragma unroll
    for (int n=0;n<4;n++) acc[m][n] = (f32x4){0.f,0.f,0.f,0.f};

  const int lr = l & 15, lk = l >> 4;
  for (int it = 0; it < kiters; ++it) {
    {
      int s = tid;
      int row = s >> 2, kg = s & 3;
      u32x4 va = *(const u32x4*)(Ab + (long)row*lda + (long)it*32 + kg*8);
      u32x4 vb = *(const u32x4*)(Bb + (long)row*ldb + (long)it*32 + kg*8);
      int sw = ((kg + row) & 3) * 8;
      *(u32x4*)&As[row*32 + sw] = va;
      *(u32x4*)&Bs[row*32 + sw] = vb;
      s = tid + 256;
      row = s >> 2; kg = s & 3;
      va = *(const u32x4*)(Ab + (long)row*lda + (long)it*32 + kg*8);
      vb = *(const u32x4*)(Bb + (long)row*ldb + (long)it*32 + kg*8);
      sw = ((kg + row) & 3) * 8;
      *(u32x4*)&As[row*32 + sw] = va;
      *(u32x4*)&Bs[row*32 + sw] = vb;
    }
    __syncthreads();
    bf16x8 af[4], bfr[4];
#pragma unroll
    for (int m=0;m<4;m++) {
      int row = wr*64 + m*16 + lr;
      af[m] = *(const bf16x8*)&As[row*32 + (((lk + row)&3)*8)];
    }
#pragma unroll
    for (int n=0;n<4;n++) {
      int row = wc*64 + n*16 + lr;
      bfr[n] = *(const bf16x8*)&Bs[row*32 + (((lk + row)&3)*8)];
    }
#pragma unroll
    for (int m=0;m<4;m++)
#pragma unroll
      for (int n=0;n<4;n++)
        acc[m][n] = __builtin_amdgcn_mfma_f32_16x16x32_bf16(af[m], bfr[n], acc[m][n], 0, 0, 0);
    __syncthreads();
  }
#pragma unroll
  for (int m=0;m<4;m++) {
#pragma unroll
    for (int n=0;n<4;n++) {
#pragma unroll
      for (int v=0;v<4;v++) {
        int r  = wr*64 + m*16 + lk*4 + v;
        int cn = wc*64 + n*16 + lr;
        long gr = (long)blockIdx.x*128 + r;
        long gc = (long)blockIdx.y*128 + cn;
        float val = acc[m][n][v];
        if (EPI == 0) {
          Cf[((long)blockIdx.z*1024 + gr)*ldc + gc] = val;
        } else if (EPI == 1) {
          float y = val + bias[gc];
          y = y > 0.f ? y : 0.f;
          Cb[gr*ldc + gc] = f2bf(y);
        } else if (EPI == 2) {
          Cf[gr*ldc + gc] = val + bias[gc];
        } else if (EPI == 3) {
          if (gc < nGuard) Cf[gr*ldc + gc] = sigf(val + bias[gc]);
        }
      }
    }
  }
}

// sum split-K partials + bias + relu -> bf16 h1b
__global__ void reduce1(const float* __restrict__ P, const float* __restrict__ b1,
                        u16* __restrict__ h1b){
  int idx = blockIdx.x*256 + threadIdx.x;        // grid 2048 -> 524288 = 1024*512
  float s = b1[idx & 511];
#pragma unroll
  for (int kc = 0; kc < 32; ++kc) s += P[(long)kc*524288 + idx];
  h1b[idx] = f2bf(s > 0.f ? s : 0.f);
}

// ---------------- sequential scan: 1024 threads, block 0; blocks >=1 convert dec_w2 ----------------
// Design r6: FIT the 128-VGPR budget instead of fighting it.
//  * 1024 threads (16 waves) -> VGPR<=128 is the mandatory compiler target.
//  * U split: 96 u32/thread in registers (24 named quads, loaded via asm volatile
//    global_load_dwordx4 so they can NEVER be sunk/rematerialized into the loop --
//    the r5 failure), 128 KB tail in LDS.
//  * lag history in a circular LDS buffer hist[50][256] (frees 25 VGPRs, no shift).
//  * h replicated 4x in padded LDS rows (144 B stride -> bank offset 4c) so the
//    4 c-group broadcast reads hit disjoint banks.
// Peak live regs ~119 < 128 -> no spill motive.
#define LDU(J,B) u32x4 U##J##_##B; asm volatile( \
  "global_load_dwordx4 %0, %1, off\n\ts_waitcnt vmcnt(0)" \
  : "=v"(U##J##_##B) : "v"(upack + (((J)*6+(B))*1024 + t)*4))
#define ACCJB(J,B) a##J = dot2acc(U##J##_##B[3],hb[3],dot2acc(U##J##_##B[2],hb[2],dot2acc(U##J##_##B[1],hb[1],dot2acc(U##J##_##B[0],hb[0],a##J))))
#define BBLOCK(B) { u32x4 hb = *(const u32x4*)&hlds4[c][(B)*8]; \
  ACCJB(0,B); ACCJB(1,B); ACCJB(2,B); ACCJB(3,B); }
#define TAILJ(J,S) { u32x4 ut = *(const u32x4*)&utail[(size_t)(((J)*2+(S))*1024 + t)*8]; \
  a##J = dot2acc(ut[3],hb[3],dot2acc(ut[2],hb[2],dot2acc(ut[1],hb[1],dot2acc(ut[0],hb[0],a##J)))); }
#define TBLOCK(S) { u32x4 hb = *(const u32x4*)&hlds4[c][48 + (S)*8]; \
  TAILJ(0,S); TAILJ(1,S); TAILJ(2,S); TAILJ(3,S); }

__global__ __launch_bounds__(1024)
void scan_kernel(const u32* __restrict__ upack, const u32x4* __restrict__ utail_img,
                 const float* __restrict__ xw, u16* __restrict__ hsb,
                 const float* __restrict__ dec_w2, u16* __restrict__ w2db){
  __shared__ u16   utail[65536];                 // 131072 B
  __shared__ float preact[1024];                 // 4096 B   (index o = g*256+e)
  __shared__ u16   hist[50*256];                 // 25600 B  circular lag buffer
  __shared__ u16   hlds4[4][72];                 // 576 B    h replicated 4x, padded
                                                 // total 161,344 B <= 163,840 B

  if (blockIdx.x != 0) {
    // dec_w2 (50000x512) f32 -> w2db (50048x512) bf16, rows >= 50000 zeroed.
    const long total = (50048L*512)/4;           // u16x4 groups
    const long stride = (long)(gridDim.x - 1)*1024;
    for (long g2 = (long)(blockIdx.x-1)*1024 + threadIdx.x; g2 < total; g2 += stride) {
      long base = g2*4;
      long row = base >> 9;
      u16x4 v;
      if (row < 50000) {
        const float* s = dec_w2 + base;
        v[0]=f2bf(s[0]); v[1]=f2bf(s[1]); v[2]=f2bf(s[2]); v[3]=f2bf(s[3]);
      } else { v[0]=0; v[1]=0; v[2]=0; v[3]=0; }
      *(u16x4*)(w2db + base) = v;
    }
    return;
  }

  const int t = threadIdx.x;
  const int c = t & 3;
  const int q = t >> 2;

  // 24 named U quads (96 u32/thread), pinned by asm volatile loads
  LDU(0,0); LDU(0,1); LDU(0,2); LDU(0,3); LDU(0,4); LDU(0,5);
  LDU(1,0); LDU(1,1); LDU(1,2); LDU(1,3); LDU(1,4); LDU(1,5);
  LDU(2,0); LDU(2,1); LDU(2,2); LDU(2,3); LDU(2,4); LDU(2,5);
  LDU(3,0); LDU(3,1); LDU(3,2); LDU(3,3); LDU(3,4); LDU(3,5);

#pragma unroll
  for (int i = 0; i < 8; ++i)
    ((u32x4*)utail)[i*1024 + t] = utail_img[i*1024 + t];

  for (int i = t; i < 50*256; i += 1024) hist[i] = 0;
  if (t < 288) { if (t < 4*72) ((u16*)hlds4)[t] = 0; }
  __syncthreads();

  int cur_pos = 0;                               // slot where THIS step's cur goes (st % 50)
  for (int st = 0; st < 1024; ++st) {
    float xw0=0.f, xw1=0.f, xw2=0.f, xw3=0.f;
    if (t < 256) {                               // prefetch; consumed in phase B
      xw0 = xw[st*1024 + t];
      xw1 = xw[st*1024 + 256 + t];
      xw2 = xw[st*1024 + 512 + t];
      xw3 = xw[st*1024 + 768 + t];
    }
    // ---- phase A: preact[o] = sum_k h[k]*U[o][k]  (thread: 4 outputs, k in [c*64,c*64+64)) ----
    float a0=0.f,a1=0.f,a2=0.f,a3=0.f;
    BBLOCK(0); BBLOCK(1); BBLOCK(2); BBLOCK(3); BBLOCK(4); BBLOCK(5);
    TBLOCK(0); TBLOCK(1);
    a0 += __shfl_xor(a0,1); a0 += __shfl_xor(a0,2);
    a1 += __shfl_xor(a1,1); a1 += __shfl_xor(a1,2);
    a2 += __shfl_xor(a2,1); a2 += __shfl_xor(a2,2);
    a3 += __shfl_xor(a3,1); a3 += __shfl_xor(a3,2);
    if (c == 0) *(f32x4*)&preact[q*4] = (f32x4){a0,a1,a2,a3};
    __syncthreads();

    // ---- phase B: gates + lag-memory + h update (threads 0..255, e = t) ----
    if (t < 256) {
      float pd = preact[t]       + xw0;
      float pi = preact[256 + t] + xw1;
      float po = preact[512 + t] + xw2;
      float pc = preact[768 + t] + xw3;
      float d  = 0.5f * sigf(pd);
      float gi = sigf(pi);
      float go = sigf(po);
      float ct = tanh_f(pc);
      float cur = gi * ct;
      // mem = sum_k w_k*hist_k ; w_0=1, w_k = w_{k-1}*((d+k-1)/k)  (== exp(gammaln ratio))
      float mem0 = cur, mem1 = 0.0f;
      float wk = 1.0f;
      int idx = cur_pos;
#pragma unroll
      for (int k = 1; k < 50; ++k) {
        idx = (idx == 0) ? 49 : idx - 1;         // slot of step st-k
        wk *= (d + (float)(k-1)) * (1.0f/(float)k);
        float hv = (float)__builtin_bit_cast(_Float16, hist[idx*256 + t]);
        if (k & 1) mem1 += wk * hv; else mem0 += wk * hv;
      }
      float hnew = go * tanh_f(mem0 + mem1);
      hist[cur_pos*256 + t] = f2h(cur);          // insert current i*ct
      hlds4[t >> 6][t & 63] = f2h(hnew);         // update h replica
      hsb[st*256 + t] = f2bf(hnew);
    }
    __syncthreads();
    cur_pos = (cur_pos == 49) ? 0 : cur_pos + 1;
  }
}

// ---------------- launcher ----------------
extern "C" void kernel_launch(void* const* d_in, const int* in_sizes, int n_in,
                              void* d_out, int out_size, void* d_ws, size_t ws_size,
                              hipStream_t stream){
  const float* x      = (const float*)d_in[0];
  const float* enc_w1 = (const float*)d_in[1];
  const float* enc_b1 = (const float*)d_in[2];
  const float* enc_w2 = (const float*)d_in[3];
  const float* enc_b2 = (const float*)d_in[4];
  const float* d_u_w  = (const float*)d_in[5];  const float* d_u_b = (const float*)d_in[6];
  const float* d_w_w  = (const float*)d_in[7];  const float* d_w_b = (const float*)d_in[8];
  const float* i_u_w  = (const float*)d_in[9];  const float* i_u_b = (const float*)d_in[10];
  const float* i_w_w  = (const float*)d_in[11]; const float* i_w_b = (const float*)d_in[12];
  const float* o_u_w  = (const float*)d_in[13]; const float* o_u_b = (const float*)d_in[14];
  const float* o_w_w  = (const float*)d_in[15]; const float* o_w_b = (const float*)d_in[16];
  const float* c_u_w  = (const float*)d_in[17]; const float* c_u_b = (const float*)d_in[18];
  const float* c_w_w  = (const float*)d_in[19]; const float* c_w_b = (const float*)d_in[20];
  const float* dec_w1 = (const float*)d_in[21]; const float* dec_b1 = (const float*)d_in[22];
  const float* dec_w2 = (const float*)d_in[23]; const float* dec_b2 = (const float*)d_in[24];

  char* ws = (char*)d_ws;
  u16*   xb     = (u16*)(ws + 0L);                 // 1024*50176*2
  u16*   w1b    = (u16*)(ws + 102760448L);         // 512*50176*2
  u16*   w2db   = (u16*)(ws + 154140672L);         // 50048*512*2
  u16*   h1b    = (u16*)(ws + 205389824L);         // 1024*512*2
  u16*   e_b    = (u16*)(ws + 206438400L);         // 1024*256*2
  u16*   wgb    = (u16*)(ws + 206962688L);         // 1024*256*2
  u16*   w2eb   = (u16*)(ws + 207486976L);         // 256*512*2
  u16*   wd1b   = (u16*)(ws + 207749120L);         // 512*256*2
  u16*   d1b    = (u16*)(ws + 208011264L);         // 1024*512*2
  u16*   hsb    = (u16*)(ws + 209059840L);         // 1024*256*2
  float* xw     = (float*)(ws + 209584128L);       // 1024*1024*4
  float* bws    = (float*)(ws + 213778432L);       // 1024*4
  u32*   upack  = (u32*)(ws + 213782528L);         // 24*1024*4 u32 *4B = 393216 B
  u16*   utailI = (u16*)(ws + 214175744L);         // 8*1024*16 B = 131072 B
  float* out    = (float*)d_out;
  float* P      = (float*)d_out;                   // split-K partials reuse d_out

  conv_x   <<<dim3(49,1024), 256, 0, stream>>>(x, xb);
  conv_w1  <<<dim3(49,512),  256, 0, stream>>>(enc_w1, w1b);
  conv_misc<<<2048, 256, 0, stream>>>(enc_w2, dec_w1, d_w_w, i_w_w, o_w_w, c_w_w, w2eb, wd1b, wgb);
  pack_bias<<<4, 256, 0, stream>>>(d_u_b, d_w_b, i_u_b, i_w_b, o_u_b, o_w_b, c_u_b, c_w_b, bws);
  pack_u   <<<1, 1024, 0, stream>>>(d_u_w, i_u_w, o_u_w, c_u_w, upack, utailI);

  gemm_bt<0><<<dim3(8,4,32), 256, 0, stream>>>(xb, w1b, nullptr, P, nullptr, 50176, 50176, 512, 49, 0);
  reduce1<<<2048, 256, 0, stream>>>(P, enc_b1, h1b);
  gemm_bt<1><<<dim3(8,2,1), 256, 0, stream>>>(h1b, w2eb, enc_b2, nullptr, e_b, 512, 512, 256, 16, 0);
  gemm_bt<2><<<dim3(8,8,1), 256, 0, stream>>>(e_b, wgb, bws, xw, nullptr, 256, 256, 1024, 8, 0);
  // sequential recurrence (block 0) + dec_w2 bf16 convert (blocks 1..196)
  scan_kernel<<<197, 1024, 0, stream>>>(upack, (const u32x4*)utailI, xw, hsb, dec_w2, w2db);
  gemm_bt<1><<<dim3(8,4,1), 256, 0, stream>>>(hsb, wd1b, dec_b1, nullptr, d1b, 256, 256, 512, 8, 0);
  gemm_bt<3><<<dim3(8,391,1), 256, 0, stream>>>(d1b, w2db, dec_b2, out, nullptr, 512, 512, 50000, 16, 50000);
}

// Round 9
// 3888.909 us; speedup vs baseline: 8.4090x; 1.7120x over previous
//
#include <hip/hip_runtime.h>

typedef unsigned int u32;
typedef unsigned short u16;
typedef __attribute__((ext_vector_type(4))) u32 u32x4;
typedef __attribute__((ext_vector_type(4))) u16 u16x4;
typedef __attribute__((ext_vector_type(8))) short bf16x8;
typedef __attribute__((ext_vector_type(4))) float f32x4;
typedef __attribute__((ext_vector_type(2))) _Float16 h2f;

#define NSC 8          // scan blocks
#define SLICE 32       // e per scan block
#define ROWS 128       // 4 gates * SLICE preact rows per block

__device__ __forceinline__ u16 f2bf(float x){
  u32 u = __builtin_bit_cast(u32, x);
  u = (u + 0x7fffu + ((u >> 16) & 1u)) >> 16;
  return (u16)u;
}
__device__ __forceinline__ u16 f2h(float x){
  _Float16 h = (_Float16)x;
  return __builtin_bit_cast(u16, h);
}
__device__ __forceinline__ float h2fl(u16 v){ return (float)__builtin_bit_cast(_Float16, v); }
__device__ __forceinline__ h2f as_h2(u32 v){ return __builtin_bit_cast(h2f, v); }
__device__ __forceinline__ float sigf(float x){ return 1.0f/(1.0f + __expf(-x)); }
__device__ __forceinline__ float tanh_f(float x){ float e = __expf(2.0f*x); return 1.0f - 2.0f/(e + 1.0f); }

__device__ __forceinline__ float dot2acc(u32 a, u32 b, float acc){
#if __has_builtin(__builtin_amdgcn_fdot2)
  return __builtin_amdgcn_fdot2(as_h2(a), as_h2(b), acc, false);
#else
  h2f ha = as_h2(a), hb = as_h2(b);
  return acc + (float)ha[0]*(float)hb[0] + (float)ha[1]*(float)hb[1];
#endif
}
__device__ __forceinline__ float dot4(u32x4 u, u32x4 h, float acc){
  acc = dot2acc(u[0], h[0], acc); acc = dot2acc(u[1], h[1], acc);
  acc = dot2acc(u[2], h[2], acc); acc = dot2acc(u[3], h[3], acc);
  return acc;
}

// ---------------- conversion kernels ----------------

// x (1024 x 50001) f32 -> xb (1024 x 50176) bf16, zero-pad cols [50000,50176)
__global__ void conv_x(const float* __restrict__ x, u16* __restrict__ xb){
  int col4 = (blockIdx.x*256 + threadIdx.x)*4;   // grid (49, 1024)
  int row  = blockIdx.y;
  const float* src = x + (long)row*50001 + col4;
  u16x4 v;
  if (col4 < 50000) { v[0]=f2bf(src[0]); v[1]=f2bf(src[1]); v[2]=f2bf(src[2]); v[3]=f2bf(src[3]); }
  else { v[0]=0; v[1]=0; v[2]=0; v[3]=0; }
  *(u16x4*)(xb + (long)row*50176 + col4) = v;
}

// enc_w1 (512 x 50000) f32 -> w1b (512 x 50176) bf16 padded
__global__ void conv_w1(const float* __restrict__ w, u16* __restrict__ wb){
  int col4 = (blockIdx.x*256 + threadIdx.x)*4;   // grid (49, 512)
  int row  = blockIdx.y;
  const float* src = w + (long)row*50000 + col4;
  u16x4 v;
  if (col4 < 50000) { v[0]=f2bf(src[0]); v[1]=f2bf(src[1]); v[2]=f2bf(src[2]); v[3]=f2bf(src[3]); }
  else { v[0]=0; v[1]=0; v[2]=0; v[3]=0; }
  *(u16x4*)(wb + (long)row*50176 + col4) = v;
}

// enc_w2 (256x512), dec_w1 (512x256), gate W_w stacked -> bf16
__global__ void conv_misc(const float* __restrict__ enc_w2, const float* __restrict__ dec_w1,
                          const float* __restrict__ dw, const float* __restrict__ iw,
                          const float* __restrict__ ow, const float* __restrict__ cw,
                          u16* __restrict__ w2eb, u16* __restrict__ wd1b, u16* __restrict__ wgb){
  int idx = blockIdx.x*256 + threadIdx.x;        // grid 2048
  if (idx < 131072) {
    w2eb[idx] = f2bf(enc_w2[idx]);
  } else if (idx < 262144) {
    int i = idx - 131072;
    wd1b[i] = f2bf(dec_w1[i]);
  } else {
    int i = idx - 262144;                        // 262144 elems: wgb[o][k], o = g*256+e
    int o = i >> 8, k = i & 255;
    int g = o >> 8, e = o & 255;
    const float* W = (g==0) ? dw : (g==1) ? iw : (g==2) ? ow : cw;
    wgb[i] = f2bf(W[e*256 + k]);
  }
}

// combined gate biases: bws[o] = u_b[e] + w_b[e]
__global__ void pack_bias(const float* dub, const float* dwb, const float* iub, const float* iwb,
                          const float* oub, const float* owb, const float* cub, const float* cwb,
                          float* __restrict__ bws){
  int o = blockIdx.x*256 + threadIdx.x;          // grid 4
  int g = o >> 8, e = o & 255;
  float v;
  if      (g==0) v = dub[e] + dwb[e];
  else if (g==1) v = iub[e] + iwb[e];
  else if (g==2) v = oub[e] + owb[e];
  else           v = cub[e] + cwb[e];
  bws[o] = v;
}

// Pack U into per-scan-block swizzled LDS images (f16).
// Block b owns rows lr in [0,128): gate g = lr>>5, e = b*32 + (lr&31).
// LDS byte layout: lr*512 + (granule16 ^ ((lr>>1)&7))*16 + (k*2)%16, granule16 = k>>3.
__global__ void pack_u(const float* du, const float* iu, const float* ou, const float* cu,
                       u16* __restrict__ upak){
  int b = blockIdx.x;                            // grid NSC x 512
  int t = threadIdx.x;
  for (int idx = t; idx < ROWS*256; idx += 512) {
    int lr = idx >> 8, k = idx & 255;
    int g = lr >> 5, e = b*SLICE + (lr & 31);
    const float* U = (g==0) ? du : (g==1) ? iu : (g==2) ? ou : cu;
    u16 val = f2h(U[e*256 + k]);
    int dst = lr*256 + ((((k>>3) ^ ((lr>>1)&7)) << 3) | (k & 7));
    upak[b*32768 + dst] = val;
  }
}

// ---------------- MFMA GEMM: C = A @ B^T, A[M][K] bf16, B[N][K] bf16 ----------------
// EPI: 0 = store f32 partial at Cf + z*1024*ldc (split-K)
//      1 = bias + relu -> bf16 Cb
//      2 = bias -> f32 Cf
//      3 = bias + sigmoid -> f32 Cf with col < nGuard
template<int EPI>
__global__ __launch_bounds__(256)
void gemm_bt(const u16* __restrict__ A, const u16* __restrict__ B,
             const float* __restrict__ bias, float* __restrict__ Cf, u16* __restrict__ Cb,
             int lda, int ldb, int ldc, int kiters, int nGuard){
  __shared__ u16 As[128*32];
  __shared__ u16 Bs[128*32];
  const int tid = threadIdx.x;
  const int l = tid & 63;
  const int w = tid >> 6;
  const int wr = w >> 1, wc = w & 1;             // 2x2 wave grid, 64x64 per wave
  const long kchunk = (long)blockIdx.z * kiters * 32;
  const u16* Ab = A + (long)blockIdx.x*128*lda + kchunk;
  const u16* Bb = B + (long)blockIdx.y*128*ldb + kchunk;
  f32x4 acc[4][4];
#pragma unroll
  for (int m=0;m<4;m++)
#pragma unroll
    for (int n=0;n<4;n++) acc[m][n] = (f32x4){0.f,0.f,0.f,0.f};

  const int lr = l & 15, lk = l >> 4;
  for (int it = 0; it < kiters; ++it) {
    {
      int s = tid;
      int row = s >> 2, kg = s & 3;
      u32x4 va = *(const u32x4*)(Ab + (long)row*lda + (long)it*32 + kg*8);
      u32x4 vb = *(const u32x4*)(Bb + (long)row*ldb + (long)it*32 + kg*8);
      int sw = ((kg + row) & 3) * 8;
      *(u32x4*)&As[row*32 + sw] = va;
      *(u32x4*)&Bs[row*32 + sw] = vb;
      s = tid + 256;
      row = s >> 2; kg = s & 3;
      va = *(const u32x4*)(Ab + (long)row*lda + (long)it*32 + kg*8);
      vb = *(const u32x4*)(Bb + (long)row*ldb + (long)it*32 + kg*8);
      sw = ((kg + row) & 3) * 8;
      *(u32x4*)&As[row*32 + sw] = va;
      *(u32x4*)&Bs[row*32 + sw] = vb;
    }
    __syncthreads();
    bf16x8 af[4], bfr[4];
#pragma unroll
    for (int m=0;m<4;m++) {
      int row = wr*64 + m*16 + lr;
      af[m] = *(const bf16x8*)&As[row*32 + (((lk + row)&3)*8)];
    }
#pragma unroll
    for (int n=0;n<4;n++) {
      int row = wc*64 + n*16 + lr;
      bfr[n] = *(const bf16x8*)&Bs[row*32 + (((lk + row)&3)*8)];
    }
#pragma unroll
    for (int m=0;m<4;m++)
#pragma unroll
      for (int n=0;n<4;n++)
        acc[m][n] = __builtin_amdgcn_mfma_f32_16x16x32_bf16(af[m], bfr[n], acc[m][n], 0, 0, 0);
    __syncthreads();
  }
#pragma unroll
  for (int m=0;m<4;m++) {
#pragma unroll
    for (int n=0;n<4;n++) {
#pragma unroll
      for (int v=0;v<4;v++) {
        int r  = wr*64 + m*16 + lk*4 + v;
        int cn = wc*64 + n*16 + lr;
        long gr = (long)blockIdx.x*128 + r;
        long gc = (long)blockIdx.y*128 + cn;
        float val = acc[m][n][v];
        if (EPI == 0) {
          Cf[((long)blockIdx.z*1024 + gr)*ldc + gc] = val;
        } else if (EPI == 1) {
          float y = val + bias[gc];
          y = y > 0.f ? y : 0.f;
          Cb[gr*ldc + gc] = f2bf(y);
        } else if (EPI == 2) {
          Cf[gr*ldc + gc] = val + bias[gc];
        } else if (EPI == 3) {
          if (gc < nGuard) Cf[gr*ldc + gc] = sigf(val + bias[gc]);
        }
      }
    }
  }
}

// sum split-K partials + bias + relu -> bf16 h1b
__global__ void reduce1(const float* __restrict__ P, const float* __restrict__ b1,
                        u16* __restrict__ h1b){
  int idx = blockIdx.x*256 + threadIdx.x;        // grid 2048 -> 524288 = 1024*512
  float s = b1[idx & 511];
#pragma unroll
  for (int kc = 0; kc < 32; ++kc) s += P[(long)kc*524288 + idx];
  h1b[idx] = f2bf(s > 0.f ? s : 0.f);
}

// ---------------- 8-block cooperative scan (blocks 0..NSC-1); blocks >= NSC convert dec_w2 ----
// r2-r6: 4 register-residency strategies all failed (allocator pins 128/64 VGPRs,
// spills or streams U every step). This design needs NO register residency:
// each block's 64 KB U-slice lives in LDS; the 512-B h vector is exchanged per
// step through a double-buffered global mailbox + agent-scope atomic counter.
// Race-freedom: reader of hmail[st&1] at step st is protected because the next
// writer of that parity (a block at step st+1) must first observe ctr >= NSC*(st+1),
// which requires the reader to have finished step st (read precedes increment).
// Liveness: 197 blocks <= 256 CUs (LDS 2/CU, waves 4/CU) -> all scan blocks
// co-resident regardless of dispatch order; ctr is monotone within a launch.
__global__ __launch_bounds__(512)
void scan_kernel(const u32x4* __restrict__ upak, const float* __restrict__ xw,
                 u16* __restrict__ hsb, const float* __restrict__ dec_w2,
                 u16* __restrict__ w2db, u32* __restrict__ hmail, u32* __restrict__ ctr){
  __shared__ __align__(16) u16 U_lds[ROWS*256];  // 65536 B, swizzled
  __shared__ __align__(16) u16 h_lds[256];       // 512 B
  __shared__ float preact[ROWS];                 // 512 B
  __shared__ u16   hist[50*34];                  // 3400 B, stride 34, cols [0,32) used
  __shared__ float inv_lds[50];                  // 1/k table
  const int b = blockIdx.x;
  const int t = threadIdx.x;

  if (b >= NSC) {
    // dec_w2 (50000x512) f32 -> w2db (50048x512) bf16, rows >= 50000 zeroed.
    const long total = (50048L*512)/4;           // u16x4 groups
    const long stride = (long)(gridDim.x - NSC)*512;
    for (long g2 = (long)(b-NSC)*512 + t; g2 < total; g2 += stride) {
      long base = g2*4;
      long row = base >> 9;
      u16x4 v;
      if (row < 50000) {
        const float* s = dec_w2 + base;
        v[0]=f2bf(s[0]); v[1]=f2bf(s[1]); v[2]=f2bf(s[2]); v[3]=f2bf(s[3]);
      } else { v[0]=0; v[1]=0; v[2]=0; v[3]=0; }
      *(u16x4*)(w2db + base) = v;
    }
    return;
  }

  // ---- init ----
#pragma unroll
  for (int i = 0; i < 8; ++i)
    ((u32x4*)U_lds)[i*512 + t] = upak[b*4096 + i*512 + t];
  for (int i = t; i < 50*34; i += 512) hist[i] = 0;
  if (t < 128) ((u32*)h_lds)[t] = 0;
  if (t < 50) inv_lds[t] = (t == 0) ? 1.0f : (1.0f/(float)t);
  __syncthreads();

  const int kc = t & 7;                          // k-chunk of 32
  const int rq = t >> 3;                         // [0,64): rows 2rq, 2rq+1
  const int swz = (rq & 7) << 4;
  const int e_loc = t >> 3;                      // phase B (t<256): element
  const int tau = t & 7;                         // phase B lane-in-group
  const int e_glob = b*SLICE + (e_loc & (SLICE-1));

  for (int st = 0; st < 1024; ++st) {
    // prefetch gate inputs (consumed in phase B; independent of mailbox)
    float xg0=0.f, xg1=0.f, xg2=0.f, xg3=0.f;
    if (t < 256) {
      xg0 = xw[st*1024 +       e_glob];
      xg1 = xw[st*1024 + 256 + e_glob];
      xg2 = xw[st*1024 + 512 + e_glob];
      xg3 = xw[st*1024 + 768 + e_glob];
    }
    // ---- wait for all slices of h(st), load mailbox -> h_lds ----
    if (st > 0) {
      if (t == 0) {
        u32 tgt = (u32)(NSC*st);
        while (__hip_atomic_load(ctr, __ATOMIC_ACQUIRE, __HIP_MEMORY_SCOPE_AGENT) < tgt)
          __builtin_amdgcn_s_sleep(1);
      }
      __syncthreads();
      if (t < 128)
        ((u32*)h_lds)[t] = __hip_atomic_load(&hmail[(st&1)*128 + t],
                                             __ATOMIC_ACQUIRE, __HIP_MEMORY_SCOPE_AGENT);
      __syncthreads();
    }
    // ---- phase A: preact[lr] = sum_k U[lr][k] * h[k] ----
    float a0 = 0.f, a1 = 0.f;
#pragma unroll
    for (int p = 0; p < 4; ++p) {
      u32x4 hb = *(const u32x4*)((const char*)h_lds + kc*64 + p*16);
      u32x4 u0 = *(const u32x4*)((const char*)U_lds + (2*rq  )*512 + ((kc*64 + p*16) ^ swz));
      u32x4 u1 = *(const u32x4*)((const char*)U_lds + (2*rq+1)*512 + ((kc*64 + p*16) ^ swz));
      a0 = dot4(u0, hb, a0);
      a1 = dot4(u1, hb, a1);
    }
    a0 += __shfl_xor(a0,1); a0 += __shfl_xor(a0,2); a0 += __shfl_xor(a0,4);
    a1 += __shfl_xor(a1,1); a1 += __shfl_xor(a1,2); a1 += __shfl_xor(a1,4);
    if (kc == 0) { preact[2*rq] = a0; preact[2*rq+1] = a1; }
    __syncthreads();

    // ---- phase B (t<256): 8 lanes per element ----
    if (t < 256) {
      float pd = preact[0*SLICE + e_loc] + xg0;
      float pi = preact[1*SLICE + e_loc] + xg1;
      float po = preact[2*SLICE + e_loc] + xg2;
      float pc = preact[3*SLICE + e_loc] + xg3;
      float d  = 0.5f * sigf(pd);
      float gi = sigf(pi);
      float go = sigf(po);
      float ct = tanh_f(pc);
      float cur = gi * ct;
      // w_k = prod_{j<k} (d+j)/(j+1)  (== exp(gammaln(d+k)-gammaln(d)-gammaln(k+1)))
      // segmented product-scan: lane tau covers k in [7tau+1, 7tau+7]; tau=7 idle.
      float c = 1.f;
      if (tau < 7) {
#pragma unroll
        for (int m = 0; m < 7; ++m) {
          int j = 7*tau + m;                     // j <= 48
          c *= (d + (float)j) * inv_lds[j+1];
        }
      }
      float v = c;
      float s1 = __shfl_up(v,1,8); if (tau >= 1) v *= s1;
      float s2 = __shfl_up(v,2,8); if (tau >= 2) v *= s2;
      float s4 = __shfl_up(v,4,8); if (tau >= 4) v *= s4;
      float S = __shfl_up(v,1,8); if (tau == 0) S = 1.f;   // S = w_{7tau}
      int base = st % 50;
      float r = S, memp = 0.f;
      if (tau < 7) {
#pragma unroll
        for (int m = 0; m < 7; ++m) {
          int k = 7*tau + 1 + m;                 // 1..49
          r *= (d + (float)(k-1)) * inv_lds[k];  // r = w_k
          int sl = base - k; if (sl < 0) sl += 50;
          memp += r * h2fl(hist[sl*34 + e_loc]);
        }
      }
      memp += __shfl_xor(memp,1,8); memp += __shfl_xor(memp,2,8); memp += __shfl_xor(memp,4,8);
      float mem = memp + cur;                    // + k=0 term (w_0 = 1)
      float hnew = go * tanh_f(mem);
      u32 lo = (u32)f2h(hnew);
      u32 hi = __shfl_down(lo, 8);               // partner element e_loc+1 (same wave)
      if (tau == 0) {
        hist[base*34 + e_loc] = f2h(cur);
        hsb[st*256 + e_glob] = f2bf(hnew);
        if ((e_loc & 1) == 0)
          __hip_atomic_store(&hmail[((st+1)&1)*128 + (e_glob>>1)], lo | (hi<<16),
                             __ATOMIC_RELEASE, __HIP_MEMORY_SCOPE_AGENT);
      }
    }
    __syncthreads();                             // drains all stores (vmcnt) block-wide
    if (t == 0)
      __hip_atomic_fetch_add(ctr, 1u, __ATOMIC_RELEASE, __HIP_MEMORY_SCOPE_AGENT);
  }
}

// ---------------- launcher ----------------
extern "C" void kernel_launch(void* const* d_in, const int* in_sizes, int n_in,
                              void* d_out, int out_size, void* d_ws, size_t ws_size,
                              hipStream_t stream){
  const float* x      = (const float*)d_in[0];
  const float* enc_w1 = (const float*)d_in[1];
  const float* enc_b1 = (const float*)d_in[2];
  const float* enc_w2 = (const float*)d_in[3];
  const float* enc_b2 = (const float*)d_in[4];
  const float* d_u_w  = (const float*)d_in[5];  const float* d_u_b = (const float*)d_in[6];
  const float* d_w_w  = (const float*)d_in[7];  const float* d_w_b = (const float*)d_in[8];
  const float* i_u_w  = (const float*)d_in[9];  const float* i_u_b = (const float*)d_in[10];
  const float* i_w_w  = (const float*)d_in[11]; const float* i_w_b = (const float*)d_in[12];
  const float* o_u_w  = (const float*)d_in[13]; const float* o_u_b = (const float*)d_in[14];
  const float* o_w_w  = (const float*)d_in[15]; const float* o_w_b = (const float*)d_in[16];
  const float* c_u_w  = (const float*)d_in[17]; const float* c_u_b = (const float*)d_in[18];
  const float* c_w_w  = (const float*)d_in[19]; const float* c_w_b = (const float*)d_in[20];
  const float* dec_w1 = (const float*)d_in[21]; const float* dec_b1 = (const float*)d_in[22];
  const float* dec_w2 = (const float*)d_in[23]; const float* dec_b2 = (const float*)d_in[24];

  char* ws = (char*)d_ws;
  u16*   xb     = (u16*)(ws + 0L);                 // 1024*50176*2
  u16*   w1b    = (u16*)(ws + 102760448L);         // 512*50176*2
  u16*   w2db   = (u16*)(ws + 154140672L);         // 50048*512*2
  u16*   h1b    = (u16*)(ws + 205389824L);         // 1024*512*2
  u16*   e_b    = (u16*)(ws + 206438400L);         // 1024*256*2
  u16*   wgb    = (u16*)(ws + 206962688L);         // 1024*256*2
  u16*   w2eb   = (u16*)(ws + 207486976L);         // 256*512*2
  u16*   wd1b   = (u16*)(ws + 207749120L);         // 512*256*2
  u16*   d1b    = (u16*)(ws + 208011264L);         // 1024*512*2
  u16*   hsb    = (u16*)(ws + 209059840L);         // 1024*256*2
  float* xw     = (float*)(ws + 209584128L);       // 1024*1024*4
  float* bws    = (float*)(ws + 213778432L);       // 1024*4
  u16*   upak   = (u16*)(ws + 213782528L);         // NSC*32768 u16 = 524288 B (ends 214306816)
  float* out    = (float*)d_out;
  float* P      = (float*)d_out;                   // split-K partials (67 MB) reuse d_out
  // mailbox + counter in the tail of d_out (untouched until the decoder GEMM,
  // which runs after the scan and fully overwrites this region)
  u32*   hmail  = (u32*)((char*)d_out + 200000000L); // 2*128 u32 = 1 KB
  u32*   ctr    = (u32*)((char*)d_out + 200004096L); // 4 B

  hipMemsetAsync(ctr, 0, 4, stream);

  conv_x   <<<dim3(49,1024), 256, 0, stream>>>(x, xb);
  conv_w1  <<<dim3(49,512),  256, 0, stream>>>(enc_w1, w1b);
  conv_misc<<<2048, 256, 0, stream>>>(enc_w2, dec_w1, d_w_w, i_w_w, o_w_w, c_w_w, w2eb, wd1b, wgb);
  pack_bias<<<4, 256, 0, stream>>>(d_u_b, d_w_b, i_u_b, i_w_b, o_u_b, o_w_b, c_u_b, c_w_b, bws);
  pack_u   <<<NSC, 512, 0, stream>>>(d_u_w, i_u_w, o_u_w, c_u_w, upak);

  gemm_bt<0><<<dim3(8,4,32), 256, 0, stream>>>(xb, w1b, nullptr, P, nullptr, 50176, 50176, 512, 49, 0);
  reduce1<<<2048, 256, 0, stream>>>(P, enc_b1, h1b);
  gemm_bt<1><<<dim3(8,2,1), 256, 0, stream>>>(h1b, w2eb, enc_b2, nullptr, e_b, 512, 512, 256, 16, 0);
  gemm_bt<2><<<dim3(8,8,1), 256, 0, stream>>>(e_b, wgb, bws, xw, nullptr, 256, 256, 1024, 8, 0);
  // cooperative scan (blocks 0..7) + dec_w2 bf16 convert (blocks 8..196)
  scan_kernel<<<197, 512, 0, stream>>>((const u32x4*)upak, xw, hsb, dec_w2, w2db, hmail, ctr);
  gemm_bt<1><<<dim3(8,4,1), 256, 0, stream>>>(hsb, wd1b, dec_b1, nullptr, d1b, 256, 256, 512, 8, 0);
  gemm_bt<3><<<dim3(8,391,1), 256, 0, stream>>>(d1b, w2db, dec_b2, out, nullptr, 512, 512, 50000, 16, 50000);
}

// Round 10
// 3523.557 us; speedup vs baseline: 9.2810x; 1.1037x over previous
//
#include <hip/hip_runtime.h>

typedef unsigned int u32;
typedef unsigned short u16;
typedef __attribute__((ext_vector_type(4))) u32 u32x4;
typedef __attribute__((ext_vector_type(4))) u16 u16x4;
typedef __attribute__((ext_vector_type(8))) short bf16x8;
typedef __attribute__((ext_vector_type(4))) float f32x4;
typedef __attribute__((ext_vector_type(2))) _Float16 h2f;

#define NSC 8          // scan blocks
#define SLICE 32       // e per scan block
#define ROWS 128       // 4 gates * SLICE preact rows per block

__device__ __forceinline__ u16 f2bf(float x){
  u32 u = __builtin_bit_cast(u32, x);
  u = (u + 0x7fffu + ((u >> 16) & 1u)) >> 16;
  return (u16)u;
}
__device__ __forceinline__ u16 f2h(float x){
  _Float16 h = (_Float16)x;
  return __builtin_bit_cast(u16, h);
}
__device__ __forceinline__ float h2fl(u16 v){ return (float)__builtin_bit_cast(_Float16, v); }
__device__ __forceinline__ h2f as_h2(u32 v){ return __builtin_bit_cast(h2f, v); }
__device__ __forceinline__ float sigf(float x){ return 1.0f/(1.0f + __expf(-x)); }
__device__ __forceinline__ float tanh_f(float x){ float e = __expf(2.0f*x); return 1.0f - 2.0f/(e + 1.0f); }

__device__ __forceinline__ float dot2acc(u32 a, u32 b, float acc){
#if __has_builtin(__builtin_amdgcn_fdot2)
  return __builtin_amdgcn_fdot2(as_h2(a), as_h2(b), acc, false);
#else
  h2f ha = as_h2(a), hb = as_h2(b);
  return acc + (float)ha[0]*(float)hb[0] + (float)ha[1]*(float)hb[1];
#endif
}
__device__ __forceinline__ float dot4(u32x4 u, u32x4 h, float acc){
  acc = dot2acc(u[0], h[0], acc); acc = dot2acc(u[1], h[1], acc);
  acc = dot2acc(u[2], h[2], acc); acc = dot2acc(u[3], h[3], acc);
  return acc;
}

// ---------------- conversion kernels ----------------

// x (1024 x 50001) f32 -> xb (1024 x 50176) bf16, zero-pad cols [50000,50176)
__global__ void conv_x(const float* __restrict__ x, u16* __restrict__ xb){
  int col4 = (blockIdx.x*256 + threadIdx.x)*4;   // grid (49, 1024)
  int row  = blockIdx.y;
  const float* src = x + (long)row*50001 + col4;
  u16x4 v;
  if (col4 < 50000) { v[0]=f2bf(src[0]); v[1]=f2bf(src[1]); v[2]=f2bf(src[2]); v[3]=f2bf(src[3]); }
  else { v[0]=0; v[1]=0; v[2]=0; v[3]=0; }
  *(u16x4*)(xb + (long)row*50176 + col4) = v;
}

// enc_w1 (512 x 50000) f32 -> w1b (512 x 50176) bf16 padded
__global__ void conv_w1(const float* __restrict__ w, u16* __restrict__ wb){
  int col4 = (blockIdx.x*256 + threadIdx.x)*4;   // grid (49, 512)
  int row  = blockIdx.y;
  const float* src = w + (long)row*50000 + col4;
  u16x4 v;
  if (col4 < 50000) { v[0]=f2bf(src[0]); v[1]=f2bf(src[1]); v[2]=f2bf(src[2]); v[3]=f2bf(src[3]); }
  else { v[0]=0; v[1]=0; v[2]=0; v[3]=0; }
  *(u16x4*)(wb + (long)row*50176 + col4) = v;
}

// enc_w2 (256x512), dec_w1 (512x256), gate W_w stacked -> bf16
__global__ void conv_misc(const float* __restrict__ enc_w2, const float* __restrict__ dec_w1,
                          const float* __restrict__ dw, const float* __restrict__ iw,
                          const float* __restrict__ ow, const float* __restrict__ cw,
                          u16* __restrict__ w2eb, u16* __restrict__ wd1b, u16* __restrict__ wgb){
  int idx = blockIdx.x*256 + threadIdx.x;        // grid 2048
  if (idx < 131072) {
    w2eb[idx] = f2bf(enc_w2[idx]);
  } else if (idx < 262144) {
    int i = idx - 131072;
    wd1b[i] = f2bf(dec_w1[i]);
  } else {
    int i = idx - 262144;                        // 262144 elems: wgb[o][k], o = g*256+e
    int o = i >> 8, k = i & 255;
    int g = o >> 8, e = o & 255;
    const float* W = (g==0) ? dw : (g==1) ? iw : (g==2) ? ow : cw;
    wgb[i] = f2bf(W[e*256 + k]);
  }
}

// combined gate biases: bws[o] = u_b[e] + w_b[e]
__global__ void pack_bias(const float* dub, const float* dwb, const float* iub, const float* iwb,
                          const float* oub, const float* owb, const float* cub, const float* cwb,
                          float* __restrict__ bws){
  int o = blockIdx.x*256 + threadIdx.x;          // grid 4
  int g = o >> 8, e = o & 255;
  float v;
  if      (g==0) v = dub[e] + dwb[e];
  else if (g==1) v = iub[e] + iwb[e];
  else if (g==2) v = oub[e] + owb[e];
  else           v = cub[e] + cwb[e];
  bws[o] = v;
}

// Pack U into per-scan-block swizzled LDS images (f16).
// Block b owns rows lr in [0,128): gate g = lr>>5, e = b*32 + (lr&31).
// LDS byte layout: lr*512 + (granule16 ^ ((lr>>1)&7))*16 + (k*2)%16, granule16 = k>>3.
__global__ void pack_u(const float* du, const float* iu, const float* ou, const float* cu,
                       u16* __restrict__ upak){
  int b = blockIdx.x;                            // grid NSC x 512
  int t = threadIdx.x;
  for (int idx = t; idx < ROWS*256; idx += 512) {
    int lr = idx >> 8, k = idx & 255;
    int g = lr >> 5, e = b*SLICE + (lr & 31);
    const float* U = (g==0) ? du : (g==1) ? iu : (g==2) ? ou : cu;
    u16 val = f2h(U[e*256 + k]);
    int dst = lr*256 + ((((k>>3) ^ ((lr>>1)&7)) << 3) | (k & 7));
    upak[b*32768 + dst] = val;
  }
}

// ---------------- MFMA GEMM: C = A @ B^T, A[M][K] bf16, B[N][K] bf16 ----------------
// EPI: 0 = store f32 partial at Cf + z*1024*ldc (split-K)
//      1 = bias + relu -> bf16 Cb
//      2 = bias -> f32 Cf
//      3 = bias + sigmoid -> f32 Cf with col < nGuard
template<int EPI>
__global__ __launch_bounds__(256)
void gemm_bt(const u16* __restrict__ A, const u16* __restrict__ B,
             const float* __restrict__ bias, float* __restrict__ Cf, u16* __restrict__ Cb,
             int lda, int ldb, int ldc, int kiters, int nGuard){
  __shared__ u16 As[128*32];
  __shared__ u16 Bs[128*32];
  const int tid = threadIdx.x;
  const int l = tid & 63;
  const int w = tid >> 6;
  const int wr = w >> 1, wc = w & 1;             // 2x2 wave grid, 64x64 per wave
  const long kchunk = (long)blockIdx.z * kiters * 32;
  const u16* Ab = A + (long)blockIdx.x*128*lda + kchunk;
  const u16* Bb = B + (long)blockIdx.y*128*ldb + kchunk;
  f32x4 acc[4][4];
#pragma unroll
  for (int m=0;m<4;m++)
#pragma unroll
    for (int n=0;n<4;n++) acc[m][n] = (f32x4){0.f,0.f,0.f,0.f};

  const int lr = l & 15, lk = l >> 4;
  for (int it = 0; it < kiters; ++it) {
    {
      int s = tid;
      int row = s >> 2, kg = s & 3;
      u32x4 va = *(const u32x4*)(Ab + (long)row*lda + (long)it*32 + kg*8);
      u32x4 vb = *(const u32x4*)(Bb + (long)row*ldb + (long)it*32 + kg*8);
      int sw = ((kg + row) & 3) * 8;
      *(u32x4*)&As[row*32 + sw] = va;
      *(u32x4*)&Bs[row*32 + sw] = vb;
      s = tid + 256;
      row = s >> 2; kg = s & 3;
      va = *(const u32x4*)(Ab + (long)row*lda + (long)it*32 + kg*8);
      vb = *(const u32x4*)(Bb + (long)row*ldb + (long)it*32 + kg*8);
      sw = ((kg + row) & 3) * 8;
      *(u32x4*)&As[row*32 + sw] = va;
      *(u32x4*)&Bs[row*32 + sw] = vb;
    }
    __syncthreads();
    bf16x8 af[4], bfr[4];
#pragma unroll
    for (int m=0;m<4;m++) {
      int row = wr*64 + m*16 + lr;
      af[m] = *(const bf16x8*)&As[row*32 + (((lk + row)&3)*8)];
    }
#pragma unroll
    for (int n=0;n<4;n++) {
      int row = wc*64 + n*16 + lr;
      bfr[n] = *(const bf16x8*)&Bs[row*32 + (((lk + row)&3)*8)];
    }
#pragma unroll
    for (int m=0;m<4;m++)
#pragma unroll
      for (int n=0;n<4;n++)
        acc[m][n] = __builtin_amdgcn_mfma_f32_16x16x32_bf16(af[m], bfr[n], acc[m][n], 0, 0, 0);
    __syncthreads();
  }
#pragma unroll
  for (int m=0;m<4;m++) {
#pragma unroll
    for (int n=0;n<4;n++) {
#pragma unroll
      for (int v=0;v<4;v++) {
        int r  = wr*64 + m*16 + lk*4 + v;
        int cn = wc*64 + n*16 + lr;
        long gr = (long)blockIdx.x*128 + r;
        long gc = (long)blockIdx.y*128 + cn;
        float val = acc[m][n][v];
        if (EPI == 0) {
          Cf[((long)blockIdx.z*1024 + gr)*ldc + gc] = val;
        } else if (EPI == 1) {
          float y = val + bias[gc];
          y = y > 0.f ? y : 0.f;
          Cb[gr*ldc + gc] = f2bf(y);
        } else if (EPI == 2) {
          Cf[gr*ldc + gc] = val + bias[gc];
        } else if (EPI == 3) {
          if (gc < nGuard) Cf[gr*ldc + gc] = sigf(val + bias[gc]);
        }
      }
    }
  }
}

// sum split-K partials + bias + relu -> bf16 h1b
__global__ void reduce1(const float* __restrict__ P, const float* __restrict__ b1,
                        u16* __restrict__ h1b){
  int idx = blockIdx.x*256 + threadIdx.x;        // grid 2048 -> 524288 = 1024*512
  float s = b1[idx & 511];
#pragma unroll
  for (int kc = 0; kc < 32; ++kc) s += P[(long)kc*524288 + idx];
  h1b[idx] = f2bf(s > 0.f ? s : 0.f);
}

// ---------------- 8-block cooperative scan (blocks 0..NSC-1); blocks >= NSC convert dec_w2 ----
// r9: the ctr-based handshake cost ~6000 cy/step -- 8 blocks' agent-scope
// fetch_adds + 8 pollers on ONE cache line serialize at the coherence point.
// r10 protocol: NO atomic RMW anywhere. Per-block 128B mailbox line =
// {16 u32 h-data, tag} x 2 parities. Writer: 16 relaxed stores, wave-local
// s_waitcnt vmcnt(0), RELEASE tag = st+1. Reader at step st: poll 8 tags
// (ACQUIRE, read-only) for == st, then relaxed-load the 8 x 16 data words.
// Race-freedom: a block overwrites parity p only at step st+1 (tag st+2),
// gated by ALL tags == st+1, which every block publishes only after its
// step-st read of parity p completed. Mailbox zeroed per launch (captured
// memset) -> stale tags from a previous graph replay can never match.
__global__ __launch_bounds__(512)
void scan_kernel(const u32x4* __restrict__ upak, const float* __restrict__ xw,
                 u16* __restrict__ hsb, const float* __restrict__ dec_w2,
                 u16* __restrict__ w2db, u32* __restrict__ hmail){
  __shared__ __align__(16) u16 U_lds[ROWS*256];  // 65536 B, swizzled
  __shared__ __align__(16) u16 h_lds[256];       // 512 B
  __shared__ float preact[ROWS];                 // 512 B
  __shared__ u16   hist[50*34];                  // 3400 B, stride 34, cols [0,32) used
  __shared__ float inv_lds[50];                  // 1/k table
  __shared__ __align__(4) u16 hstage[32];        // staging of own h-slice for publish
  const int b = blockIdx.x;
  const int t = threadIdx.x;

  if (b >= NSC) {
    // dec_w2 (50000x512) f32 -> w2db (50048x512) bf16, rows >= 50000 zeroed.
    const long total = (50048L*512)/4;           // u16x4 groups
    const long stride = (long)(gridDim.x - NSC)*512;
    for (long g2 = (long)(b-NSC)*512 + t; g2 < total; g2 += stride) {
      long base = g2*4;
      long row = base >> 9;
      u16x4 v;
      if (row < 50000) {
        const float* s = dec_w2 + base;
        v[0]=f2bf(s[0]); v[1]=f2bf(s[1]); v[2]=f2bf(s[2]); v[3]=f2bf(s[3]);
      } else { v[0]=0; v[1]=0; v[2]=0; v[3]=0; }
      *(u16x4*)(w2db + base) = v;
    }
    return;
  }

  // ---- init ----
#pragma unroll
  for (int i = 0; i < 8; ++i)
    ((u32x4*)U_lds)[i*512 + t] = upak[b*4096 + i*512 + t];
  for (int i = t; i < 50*34; i += 512) hist[i] = 0;
  if (t < 128) ((u32*)h_lds)[t] = 0;
  if (t < 50) inv_lds[t] = (t == 0) ? 1.0f : (1.0f/(float)t);
  __syncthreads();

  const int kc = t & 7;                          // phase A: k-chunk of 32
  const int rq = t >> 3;                         // phase A: rows 2rq, 2rq+1
  const int swz = (rq & 7) << 4;
  const int e_loc = t >> 3;                      // phase B (t<256): element
  const int tau = t & 7;                         // phase B lane-in-group
  const int e_glob = b*SLICE + (e_loc & (SLICE-1));

  for (int st = 0; st < 1024; ++st) {
    // prefetch gate inputs (consumed in phase B; independent of mailbox)
    float xg0=0.f, xg1=0.f, xg2=0.f, xg3=0.f;
    if (t < 256) {
      xg0 = xw[st*1024 +       e_glob];
      xg1 = xw[st*1024 + 256 + e_glob];
      xg2 = xw[st*1024 + 512 + e_glob];
      xg3 = xw[st*1024 + 768 + e_glob];
    }
    // ---- wait for h(st): poll 8 per-block tags, then load data -> h_lds ----
    if (st > 0) {
      if (t < 8) {
        const u32* tp = hmail + (((st&1)*8 + t)<<5) + 16;
        while (__hip_atomic_load(tp, __ATOMIC_ACQUIRE, __HIP_MEMORY_SCOPE_AGENT) != (u32)st)
          __builtin_amdgcn_s_sleep(1);
      }
      __syncthreads();
      if (t < 128) {
        int j = t >> 4, w = t & 15;
        u32 v = __hip_atomic_load(hmail + (((st&1)*8 + j)<<5) + w,
                                  __ATOMIC_RELAXED, __HIP_MEMORY_SCOPE_AGENT);
        ((u32*)h_lds)[j*16 + w] = v;
      }
      __syncthreads();
    }
    // ---- phase A: preact[lr] = sum_k U[lr][k] * h[k] ----
    float a0 = 0.f, a1 = 0.f;
#pragma unroll
    for (int p = 0; p < 4; ++p) {
      u32x4 hb = *(const u32x4*)((const char*)h_lds + kc*64 + p*16);
      u32x4 u0 = *(const u32x4*)((const char*)U_lds + (2*rq  )*512 + ((kc*64 + p*16) ^ swz));
      u32x4 u1 = *(const u32x4*)((const char*)U_lds + (2*rq+1)*512 + ((kc*64 + p*16) ^ swz));
      a0 = dot4(u0, hb, a0);
      a1 = dot4(u1, hb, a1);
    }
    a0 += __shfl_xor(a0,1); a0 += __shfl_xor(a0,2); a0 += __shfl_xor(a0,4);
    a1 += __shfl_xor(a1,1); a1 += __shfl_xor(a1,2); a1 += __shfl_xor(a1,4);
    if (kc == 0) { preact[2*rq] = a0; preact[2*rq+1] = a1; }
    __syncthreads();

    // ---- phase B (t<256): 8 lanes per element ----
    u16 hnew_bf = 0;
    if (t < 256) {
      float pd = preact[0*SLICE + e_loc] + xg0;
      float pi = preact[1*SLICE + e_loc] + xg1;
      float po = preact[2*SLICE + e_loc] + xg2;
      float pc = preact[3*SLICE + e_loc] + xg3;
      float d  = 0.5f * sigf(pd);
      float gi = sigf(pi);
      float go = sigf(po);
      float ct = tanh_f(pc);
      float cur = gi * ct;
      // w_k = prod_{j<k} (d+j)/(j+1)  (== exp(gammaln(d+k)-gammaln(d)-gammaln(k+1)))
      // segmented product-scan: lane tau covers k in [7tau+1, 7tau+7]; tau=7 idle.
      float c = 1.f;
      if (tau < 7) {
#pragma unroll
        for (int m = 0; m < 7; ++m) {
          int j = 7*tau + m;                     // j <= 48
          c *= (d + (float)j) * inv_lds[j+1];
        }
      }
      float v = c;
      float s1 = __shfl_up(v,1,8); if (tau >= 1) v *= s1;
      float s2 = __shfl_up(v,2,8); if (tau >= 2) v *= s2;
      float s4 = __shfl_up(v,4,8); if (tau >= 4) v *= s4;
      float S = __shfl_up(v,1,8); if (tau == 0) S = 1.f;   // S = w_{7tau}
      int base = st % 50;
      float r = S, memp = 0.f;
      if (tau < 7) {
#pragma unroll
        for (int m = 0; m < 7; ++m) {
          int k = 7*tau + 1 + m;                 // 1..49
          r *= (d + (float)(k-1)) * inv_lds[k];  // r = w_k
          int sl = base - k; if (sl < 0) sl += 50;
          memp += r * h2fl(hist[sl*34 + e_loc]);
        }
      }
      memp += __shfl_xor(memp,1,8); memp += __shfl_xor(memp,2,8); memp += __shfl_xor(memp,4,8);
      float mem = memp + cur;                    // + k=0 term (w_0 = 1)
      float hnew = go * tanh_f(mem);
      hnew_bf = f2bf(hnew);
      if (tau == 0) {
        hist[base*34 + e_loc] = f2h(cur);
        hstage[e_loc] = f2h(hnew);
      }
    }
    __syncthreads();                             // hstage ready; no global stores pending -> cheap

    // ---- publish own slice (wave 0), then off-critical-path hsb store ----
    {
      int pp = (((st+1)&1)*8 + b) << 5;
      if (t < 16)
        __hip_atomic_store(hmail + pp + t, ((const u32*)hstage)[t],
                           __ATOMIC_RELAXED, __HIP_MEMORY_SCOPE_AGENT);
      asm volatile("s_waitcnt vmcnt(0)" ::: "memory");   // wave-local drain of the 16 data stores
      if (t == 0)
        __hip_atomic_store(hmail + pp + 16, (u32)(st+1),
                           __ATOMIC_RELEASE, __HIP_MEMORY_SCOPE_AGENT);
    }
    if (t < 256 && tau == 0)
      hsb[st*256 + e_glob] = hnew_bf;            // drained by a later barrier, not this step's
  }
}

// ---------------- launcher ----------------
extern "C" void kernel_launch(void* const* d_in, const int* in_sizes, int n_in,
                              void* d_out, int out_size, void* d_ws, size_t ws_size,
                              hipStream_t stream){
  const float* x      = (const float*)d_in[0];
  const float* enc_w1 = (const float*)d_in[1];
  const float* enc_b1 = (const float*)d_in[2];
  const float* enc_w2 = (const float*)d_in[3];
  const float* enc_b2 = (const float*)d_in[4];
  const float* d_u_w  = (const float*)d_in[5];  const float* d_u_b = (const float*)d_in[6];
  const float* d_w_w  = (const float*)d_in[7];  const float* d_w_b = (const float*)d_in[8];
  const float* i_u_w  = (const float*)d_in[9];  const float* i_u_b = (const float*)d_in[10];
  const float* i_w_w  = (const float*)d_in[11]; const float* i_w_b = (const float*)d_in[12];
  const float* o_u_w  = (const float*)d_in[13]; const float* o_u_b = (const float*)d_in[14];
  const float* o_w_w  = (const float*)d_in[15]; const float* o_w_b = (const float*)d_in[16];
  const float* c_u_w  = (const float*)d_in[17]; const float* c_u_b = (const float*)d_in[18];
  const float* c_w_w  = (const float*)d_in[19]; const float* c_w_b = (const float*)d_in[20];
  const float* dec_w1 = (const float*)d_in[21]; const float* dec_b1 = (const float*)d_in[22];
  const float* dec_w2 = (const float*)d_in[23]; const float* dec_b2 = (const float*)d_in[24];

  char* ws = (char*)d_ws;
  u16*   xb     = (u16*)(ws + 0L);                 // 1024*50176*2
  u16*   w1b    = (u16*)(ws + 102760448L);         // 512*50176*2
  u16*   w2db   = (u16*)(ws + 154140672L);         // 50048*512*2
  u16*   h1b    = (u16*)(ws + 205389824L);         // 1024*512*2
  u16*   e_b    = (u16*)(ws + 206438400L);         // 1024*256*2
  u16*   wgb    = (u16*)(ws + 206962688L);         // 1024*256*2
  u16*   w2eb   = (u16*)(ws + 207486976L);         // 256*512*2
  u16*   wd1b   = (u16*)(ws + 207749120L);         // 512*256*2
  u16*   d1b    = (u16*)(ws + 208011264L);         // 1024*512*2
  u16*   hsb    = (u16*)(ws + 209059840L);         // 1024*256*2
  float* xw     = (float*)(ws + 209584128L);       // 1024*1024*4
  float* bws    = (float*)(ws + 213778432L);       // 1024*4
  u16*   upak   = (u16*)(ws + 213782528L);         // NSC*32768 u16 = 524288 B
  float* out    = (float*)d_out;
  float* P      = (float*)d_out;                   // split-K partials (67 MB) reuse d_out
  // per-block mailbox lines in the tail of d_out (overwritten only by the
  // decoder GEMM, which runs after the scan): 2 parities x 8 blocks x 128 B
  u32*   hmail  = (u32*)((char*)d_out + 200000000L); // 2048 B, 128-aligned

  hipMemsetAsync(hmail, 0, 2048, stream);          // tags can never match a stale replay

  conv_x   <<<dim3(49,1024), 256, 0, stream>>>(x, xb);
  conv_w1  <<<dim3(49,512),  256, 0, stream>>>(enc_w1, w1b);
  conv_misc<<<2048, 256, 0, stream>>>(enc_w2, dec_w1, d_w_w, i_w_w, o_w_w, c_w_w, w2eb, wd1b, wgb);
  pack_bias<<<4, 256, 0, stream>>>(d_u_b, d_w_b, i_u_b, i_w_b, o_u_b, o_w_b, c_u_b, c_w_b, bws);
  pack_u   <<<NSC, 512, 0, stream>>>(d_u_w, i_u_w, o_u_w, c_u_w, upak);

  gemm_bt<0><<<dim3(8,4,32), 256, 0, stream>>>(xb, w1b, nullptr, P, nullptr, 50176, 50176, 512, 49, 0);
  reduce1<<<2048, 256, 0, stream>>>(P, enc_b1, h1b);
  gemm_bt<1><<<dim3(8,2,1), 256, 0, stream>>>(h1b, w2eb, enc_b2, nullptr, e_b, 512, 512, 256, 16, 0);
  gemm_bt<2><<<dim3(8,8,1), 256, 0, stream>>>(e_b, wgb, bws, xw, nullptr, 256, 256, 1024, 8, 0);
  // cooperative scan (blocks 0..7) + dec_w2 bf16 convert (blocks 8..196)
  scan_kernel<<<197, 512, 0, stream>>>((const u32x4*)upak, xw, hsb, dec_w2, w2db, hmail);
  gemm_bt<1><<<dim3(8,4,1), 256, 0, stream>>>(hsb, wd1b, dec_b1, nullptr, d1b, 256, 256, 512, 8, 0);
  gemm_bt<3><<<dim3(8,391,1), 256, 0, stream>>>(d1b, w2db, dec_b2, out, nullptr, 512, 512, 50000, 16, 50000);
}

// Round 11
// 2868.562 us; speedup vs baseline: 11.4001x; 1.2283x over previous
//
#include <hip/hip_runtime.h>

typedef unsigned int u32;
typedef unsigned short u16;
typedef __attribute__((ext_vector_type(4))) u32 u32x4;
typedef __attribute__((ext_vector_type(4))) u16 u16x4;
typedef __attribute__((ext_vector_type(8))) short bf16x8;
typedef __attribute__((ext_vector_type(4))) float f32x4;
typedef __attribute__((ext_vector_type(2))) _Float16 h2f;

#define NSC 8          // scan blocks
#define SLICE 32       // e per scan block
#define ROWS 128       // 4 gates * SLICE preact rows per block

__device__ __forceinline__ u16 f2bf(float x){
  u32 u = __builtin_bit_cast(u32, x);
  u = (u + 0x7fffu + ((u >> 16) & 1u)) >> 16;
  return (u16)u;
}
__device__ __forceinline__ u16 f2h(float x){
  _Float16 h = (_Float16)x;
  return __builtin_bit_cast(u16, h);
}
__device__ __forceinline__ float h2fl(u16 v){ return (float)__builtin_bit_cast(_Float16, v); }
__device__ __forceinline__ h2f as_h2(u32 v){ return __builtin_bit_cast(h2f, v); }
__device__ __forceinline__ float sigf(float x){ return 1.0f/(1.0f + __expf(-x)); }
__device__ __forceinline__ float tanh_f(float x){ float e = __expf(2.0f*x); return 1.0f - 2.0f/(e + 1.0f); }

__device__ __forceinline__ float dot2acc(u32 a, u32 b, float acc){
#if __has_builtin(__builtin_amdgcn_fdot2)
  return __builtin_amdgcn_fdot2(as_h2(a), as_h2(b), acc, false);
#else
  h2f ha = as_h2(a), hb = as_h2(b);
  return acc + (float)ha[0]*(float)hb[0] + (float)ha[1]*(float)hb[1];
#endif
}
__device__ __forceinline__ float dot4(u32x4 u, u32x4 h, float acc){
  acc = dot2acc(u[0], h[0], acc); acc = dot2acc(u[1], h[1], acc);
  acc = dot2acc(u[2], h[2], acc); acc = dot2acc(u[3], h[3], acc);
  return acc;
}

// ---------------- conversion kernels ----------------

// x (1024 x 50001) f32 -> xb (1024 x 50176) bf16, zero-pad cols [50000,50176)
__global__ void conv_x(const float* __restrict__ x, u16* __restrict__ xb){
  int col4 = (blockIdx.x*256 + threadIdx.x)*4;   // grid (49, 1024)
  int row  = blockIdx.y;
  const float* src = x + (long)row*50001 + col4;
  u16x4 v;
  if (col4 < 50000) { v[0]=f2bf(src[0]); v[1]=f2bf(src[1]); v[2]=f2bf(src[2]); v[3]=f2bf(src[3]); }
  else { v[0]=0; v[1]=0; v[2]=0; v[3]=0; }
  *(u16x4*)(xb + (long)row*50176 + col4) = v;
}

// enc_w1 (512 x 50000) f32 -> w1b (512 x 50176) bf16 padded
__global__ void conv_w1(const float* __restrict__ w, u16* __restrict__ wb){
  int col4 = (blockIdx.x*256 + threadIdx.x)*4;   // grid (49, 512)
  int row  = blockIdx.y;
  const float* src = w + (long)row*50000 + col4;
  u16x4 v;
  if (col4 < 50000) { v[0]=f2bf(src[0]); v[1]=f2bf(src[1]); v[2]=f2bf(src[2]); v[3]=f2bf(src[3]); }
  else { v[0]=0; v[1]=0; v[2]=0; v[3]=0; }
  *(u16x4*)(wb + (long)row*50176 + col4) = v;
}

// enc_w2 (256x512), dec_w1 (512x256), gate W_w stacked -> bf16
__global__ void conv_misc(const float* __restrict__ enc_w2, const float* __restrict__ dec_w1,
                          const float* __restrict__ dw, const float* __restrict__ iw,
                          const float* __restrict__ ow, const float* __restrict__ cw,
                          u16* __restrict__ w2eb, u16* __restrict__ wd1b, u16* __restrict__ wgb){
  int idx = blockIdx.x*256 + threadIdx.x;        // grid 2048
  if (idx < 131072) {
    w2eb[idx] = f2bf(enc_w2[idx]);
  } else if (idx < 262144) {
    int i = idx - 131072;
    wd1b[i] = f2bf(dec_w1[i]);
  } else {
    int i = idx - 262144;                        // 262144 elems: wgb[o][k], o = g*256+e
    int o = i >> 8, k = i & 255;
    int g = o >> 8, e = o & 255;
    const float* W = (g==0) ? dw : (g==1) ? iw : (g==2) ? ow : cw;
    wgb[i] = f2bf(W[e*256 + k]);
  }
}

// combined gate biases: bws[o] = u_b[e] + w_b[e]
__global__ void pack_bias(const float* dub, const float* dwb, const float* iub, const float* iwb,
                          const float* oub, const float* owb, const float* cub, const float* cwb,
                          float* __restrict__ bws){
  int o = blockIdx.x*256 + threadIdx.x;          // grid 4
  int g = o >> 8, e = o & 255;
  float v;
  if      (g==0) v = dub[e] + dwb[e];
  else if (g==1) v = iub[e] + iwb[e];
  else if (g==2) v = oub[e] + owb[e];
  else           v = cub[e] + cwb[e];
  bws[o] = v;
}

// Pack U into per-scan-block swizzled LDS images (f16).
// Block b owns rows lr in [0,128): gate g = lr>>5, e = b*32 + (lr&31).
// LDS byte layout: lr*512 + (granule16 ^ ((lr>>1)&7))*16 + (k*2)%16, granule16 = k>>3.
__global__ void pack_u(const float* du, const float* iu, const float* ou, const float* cu,
                       u16* __restrict__ upak){
  int b = blockIdx.x;                            // grid NSC x 512
  int t = threadIdx.x;
  for (int idx = t; idx < ROWS*256; idx += 512) {
    int lr = idx >> 8, k = idx & 255;
    int g = lr >> 5, e = b*SLICE + (lr & 31);
    const float* U = (g==0) ? du : (g==1) ? iu : (g==2) ? ou : cu;
    u16 val = f2h(U[e*256 + k]);
    int dst = lr*256 + ((((k>>3) ^ ((lr>>1)&7)) << 3) | (k & 7));
    upak[b*32768 + dst] = val;
  }
}

// ---------------- MFMA GEMM: C = A @ B^T, A[M][K] bf16, B[N][K] bf16 ----------------
// EPI: 0 = store f32 partial at Cf + z*1024*ldc (split-K)
//      1 = bias + relu -> bf16 Cb
//      2 = bias -> f32 Cf
//      3 = bias + sigmoid -> f32 Cf with col < nGuard
template<int EPI>
__global__ __launch_bounds__(256)
void gemm_bt(const u16* __restrict__ A, const u16* __restrict__ B,
             const float* __restrict__ bias, float* __restrict__ Cf, u16* __restrict__ Cb,
             int lda, int ldb, int ldc, int kiters, int nGuard){
  __shared__ u16 As[128*32];
  __shared__ u16 Bs[128*32];
  const int tid = threadIdx.x;
  const int l = tid & 63;
  const int w = tid >> 6;
  const int wr = w >> 1, wc = w & 1;             // 2x2 wave grid, 64x64 per wave
  const long kchunk = (long)blockIdx.z * kiters * 32;
  const u16* Ab = A + (long)blockIdx.x*128*lda + kchunk;
  const u16* Bb = B + (long)blockIdx.y*128*ldb + kchunk;
  f32x4 acc[4][4];
#pragma unroll
  for (int m=0;m<4;m++)
#pragma unroll
    for (int n=0;n<4;n++) acc[m][n] = (f32x4){0.f,0.f,0.f,0.f};

  const int lr = l & 15, lk = l >> 4;
  for (int it = 0; it < kiters; ++it) {
    {
      int s = tid;
      int row = s >> 2, kg = s & 3;
      u32x4 va = *(const u32x4*)(Ab + (long)row*lda + (long)it*32 + kg*8);
      u32x4 vb = *(const u32x4*)(Bb + (long)row*ldb + (long)it*32 + kg*8);
      int sw = ((kg + row) & 3) * 8;
      *(u32x4*)&As[row*32 + sw] = va;
      *(u32x4*)&Bs[row*32 + sw] = vb;
      s = tid + 256;
      row = s >> 2; kg = s & 3;
      va = *(const u32x4*)(Ab + (long)row*lda + (long)it*32 + kg*8);
      vb = *(const u32x4*)(Bb + (long)row*ldb + (long)it*32 + kg*8);
      sw = ((kg + row) & 3) * 8;
      *(u32x4*)&As[row*32 + sw] = va;
      *(u32x4*)&Bs[row*32 + sw] = vb;
    }
    __syncthreads();
    bf16x8 af[4], bfr[4];
#pragma unroll
    for (int m=0;m<4;m++) {
      int row = wr*64 + m*16 + lr;
      af[m] = *(const bf16x8*)&As[row*32 + (((lk + row)&3)*8)];
    }
#pragma unroll
    for (int n=0;n<4;n++) {
      int row = wc*64 + n*16 + lr;
      bfr[n] = *(const bf16x8*)&Bs[row*32 + (((lk + row)&3)*8)];
    }
#pragma unroll
    for (int m=0;m<4;m++)
#pragma unroll
      for (int n=0;n<4;n++)
        acc[m][n] = __builtin_amdgcn_mfma_f32_16x16x32_bf16(af[m], bfr[n], acc[m][n], 0, 0, 0);
    __syncthreads();
  }
#pragma unroll
  for (int m=0;m<4;m++) {
#pragma unroll
    for (int n=0;n<4;n++) {
#pragma unroll
      for (int v=0;v<4;v++) {
        int r  = wr*64 + m*16 + lk*4 + v;
        int cn = wc*64 + n*16 + lr;
        long gr = (long)blockIdx.x*128 + r;
        long gc = (long)blockIdx.y*128 + cn;
        float val = acc[m][n][v];
        if (EPI == 0) {
          Cf[((long)blockIdx.z*1024 + gr)*ldc + gc] = val;
        } else if (EPI == 1) {
          float y = val + bias[gc];
          y = y > 0.f ? y : 0.f;
          Cb[gr*ldc + gc] = f2bf(y);
        } else if (EPI == 2) {
          Cf[gr*ldc + gc] = val + bias[gc];
        } else if (EPI == 3) {
          if (gc < nGuard) Cf[gr*ldc + gc] = sigf(val + bias[gc]);
        }
      }
    }
  }
}

// sum split-K partials + bias + relu -> bf16 h1b
__global__ void reduce1(const float* __restrict__ P, const float* __restrict__ b1,
                        u16* __restrict__ h1b){
  int idx = blockIdx.x*256 + threadIdx.x;        // grid 2048 -> 524288 = 1024*512
  float s = b1[idx & 511];
#pragma unroll
  for (int kc = 0; kc < 32; ++kc) s += P[(long)kc*524288 + idx];
  h1b[idx] = f2bf(s > 0.f ? s : 0.f);
}

// ---------------- 8-block cooperative scan (blocks 0..NSC-1); blocks >= NSC convert dec_w2 ----
// r10 post-mortem: tag-then-data = TWO serial L3 round-trips per step (~7350 cy).
// r11 protocol: SELF-VALIDATING WORDS. hmail[parity][e] = (tag16<<16)|f16(h[e]).
// A single relaxed 32-bit load is atomic: when tag matches, the low half IS the
// value -- one L3 round-trip, no release fence, no vmcnt drain, no acquire.
// Race-freedom: a thread's publish (overwriting parity p at step st+1) is
// HW-ordered after its step-st poll of parity p because two __syncthreads
// (which drain vmcnt) lie between them in program order, and the publish is
// gated on ALL blocks' tags st+1 -- which exist only after every block's
// step-st poll completed. Mailbox zeroed per launch (captured memset) ->
// tag 0 never matches st >= 1; tags <= 1024 fit 16 bits.
__global__ __launch_bounds__(512)
void scan_kernel(const u32x4* __restrict__ upak, const float* __restrict__ xw,
                 u16* __restrict__ hsb, const float* __restrict__ dec_w2,
                 u16* __restrict__ w2db, u32* __restrict__ hmail){
  __shared__ __align__(16) u16 U_lds[ROWS*256];  // 65536 B, swizzled
  __shared__ __align__(16) u16 h_lds[256];       // 512 B
  __shared__ float preact[ROWS];                 // 512 B
  __shared__ u16   hist[50*34];                  // 3400 B, stride 34, cols [0,32) used
  __shared__ float inv_lds[50];                  // 1/k table
  const int b = blockIdx.x;
  const int t = threadIdx.x;

  if (b >= NSC) {
    // dec_w2 (50000x512) f32 -> w2db (50048x512) bf16, rows >= 50000 zeroed.
    const long total = (50048L*512)/4;           // u16x4 groups
    const long stride = (long)(gridDim.x - NSC)*512;
    for (long g2 = (long)(b-NSC)*512 + t; g2 < total; g2 += stride) {
      long base = g2*4;
      long row = base >> 9;
      u16x4 v;
      if (row < 50000) {
        const float* s = dec_w2 + base;
        v[0]=f2bf(s[0]); v[1]=f2bf(s[1]); v[2]=f2bf(s[2]); v[3]=f2bf(s[3]);
      } else { v[0]=0; v[1]=0; v[2]=0; v[3]=0; }
      *(u16x4*)(w2db + base) = v;
    }
    return;
  }

  // ---- init ----
#pragma unroll
  for (int i = 0; i < 8; ++i)
    ((u32x4*)U_lds)[i*512 + t] = upak[b*4096 + i*512 + t];
  for (int i = t; i < 50*34; i += 512) hist[i] = 0;
  if (t < 128) ((u32*)h_lds)[t] = 0;
  if (t < 50) inv_lds[t] = (t == 0) ? 1.0f : (1.0f/(float)t);
  __syncthreads();

  const int kc = t & 7;                          // phase A: k-chunk of 32
  const int rq = t >> 3;                         // phase A: rows 2rq, 2rq+1
  const int swz = (rq & 7) << 4;
  const int e_loc = t >> 3;                      // phase B (t<256): element
  const int tau = t & 7;                         // phase B lane-in-group
  const int e_glob = b*SLICE + (e_loc & (SLICE-1));

  for (int st = 0; st < 1024; ++st) {
    // prefetch gate inputs (consumed in phase B; independent of mailbox)
    float xg0=0.f, xg1=0.f, xg2=0.f, xg3=0.f;
    if (t < 256) {
      xg0 = xw[st*1024 +       e_glob];
      xg1 = xw[st*1024 + 256 + e_glob];
      xg2 = xw[st*1024 + 512 + e_glob];
      xg3 = xw[st*1024 + 768 + e_glob];
    }
    // ---- wait for h(st): each of 256 threads polls ITS self-validating word ----
    if (st > 0) {
      if (t < 256) {
        const u32* wp = hmail + ((st&1)<<8) + t;
        u32 v;
        do {
          v = __hip_atomic_load(wp, __ATOMIC_RELAXED, __HIP_MEMORY_SCOPE_AGENT);
        } while ((v >> 16) != (u32)st);
        h_lds[t] = (u16)v;
      }
      __syncthreads();
    }
    // ---- phase A: preact[lr] = sum_k U[lr][k] * h[k] ----
    float a0 = 0.f, a1 = 0.f;
#pragma unroll
    for (int p = 0; p < 4; ++p) {
      u32x4 hb = *(const u32x4*)((const char*)h_lds + kc*64 + p*16);
      u32x4 u0 = *(const u32x4*)((const char*)U_lds + (2*rq  )*512 + ((kc*64 + p*16) ^ swz));
      u32x4 u1 = *(const u32x4*)((const char*)U_lds + (2*rq+1)*512 + ((kc*64 + p*16) ^ swz));
      a0 = dot4(u0, hb, a0);
      a1 = dot4(u1, hb, a1);
    }
    a0 += __shfl_xor(a0,1); a0 += __shfl_xor(a0,2); a0 += __shfl_xor(a0,4);
    a1 += __shfl_xor(a1,1); a1 += __shfl_xor(a1,2); a1 += __shfl_xor(a1,4);
    if (kc == 0) { preact[2*rq] = a0; preact[2*rq+1] = a1; }
    __syncthreads();

    // ---- phase B (t<256): 8 lanes per element ----
    if (t < 256) {
      float pd = preact[0*SLICE + e_loc] + xg0;
      float pi = preact[1*SLICE + e_loc] + xg1;
      float po = preact[2*SLICE + e_loc] + xg2;
      float pc = preact[3*SLICE + e_loc] + xg3;
      float d  = 0.5f * sigf(pd);
      float gi = sigf(pi);
      float go = sigf(po);
      float ct = tanh_f(pc);
      float cur = gi * ct;
      // w_k = prod_{j<k} (d+j)/(j+1)  (== exp(gammaln(d+k)-gammaln(d)-gammaln(k+1)))
      // segmented product-scan: lane tau covers k in [7tau+1, 7tau+7]; tau=7 idle.
      float c = 1.f;
      if (tau < 7) {
#pragma unroll
        for (int m = 0; m < 7; ++m) {
          int j = 7*tau + m;                     // j <= 48
          c *= (d + (float)j) * inv_lds[j+1];
        }
      }
      float v = c;
      float s1 = __shfl_up(v,1,8); if (tau >= 1) v *= s1;
      float s2 = __shfl_up(v,2,8); if (tau >= 2) v *= s2;
      float s4 = __shfl_up(v,4,8); if (tau >= 4) v *= s4;
      float S = __shfl_up(v,1,8); if (tau == 0) S = 1.f;   // S = w_{7tau}
      int base = st % 50;
      float r = S, memp = 0.f;
      if (tau < 7) {
#pragma unroll
        for (int m = 0; m < 7; ++m) {
          int k = 7*tau + 1 + m;                 // 1..49
          r *= (d + (float)(k-1)) * inv_lds[k];  // r = w_k
          int sl = base - k; if (sl < 0) sl += 50;
          memp += r * h2fl(hist[sl*34 + e_loc]);
        }
      }
      memp += __shfl_xor(memp,1,8); memp += __shfl_xor(memp,2,8); memp += __shfl_xor(memp,4,8);
      float mem = memp + cur;                    // + k=0 term (w_0 = 1)
      float hnew = go * tanh_f(mem);
      if (tau == 0) {
        // publish FIRST (critical path), then local/bookkeeping stores
        __hip_atomic_store(hmail + ((((st+1)&1))<<8) + e_glob,
                           (((u32)(st+1)) << 16) | (u32)f2h(hnew),
                           __ATOMIC_RELAXED, __HIP_MEMORY_SCOPE_AGENT);
        hist[base*34 + e_loc] = f2h(cur);
        hsb[st*256 + e_glob] = f2bf(hnew);
      }
    }
    // no trailing barrier: the next iteration's poll-barrier orders hist/h_lds
  }
}

// ---------------- launcher ----------------
extern "C" void kernel_launch(void* const* d_in, const int* in_sizes, int n_in,
                              void* d_out, int out_size, void* d_ws, size_t ws_size,
                              hipStream_t stream){
  const float* x      = (const float*)d_in[0];
  const float* enc_w1 = (const float*)d_in[1];
  const float* enc_b1 = (const float*)d_in[2];
  const float* enc_w2 = (const float*)d_in[3];
  const float* enc_b2 = (const float*)d_in[4];
  const float* d_u_w  = (const float*)d_in[5];  const float* d_u_b = (const float*)d_in[6];
  const float* d_w_w  = (const float*)d_in[7];  const float* d_w_b = (const float*)d_in[8];
  const float* i_u_w  = (const float*)d_in[9];  const float* i_u_b = (const float*)d_in[10];
  const float* i_w_w  = (const float*)d_in[11]; const float* i_w_b = (const float*)d_in[12];
  const float* o_u_w  = (const float*)d_in[13]; const float* o_u_b = (const float*)d_in[14];
  const float* o_w_w  = (const float*)d_in[15]; const float* o_w_b = (const float*)d_in[16];
  const float* c_u_w  = (const float*)d_in[17]; const float* c_u_b = (const float*)d_in[18];
  const float* c_w_w  = (const float*)d_in[19]; const float* c_w_b = (const float*)d_in[20];
  const float* dec_w1 = (const float*)d_in[21]; const float* dec_b1 = (const float*)d_in[22];
  const float* dec_w2 = (const float*)d_in[23]; const float* dec_b2 = (const float*)d_in[24];

  char* ws = (char*)d_ws;
  u16*   xb     = (u16*)(ws + 0L);                 // 1024*50176*2
  u16*   w1b    = (u16*)(ws + 102760448L);         // 512*50176*2
  u16*   w2db   = (u16*)(ws + 154140672L);         // 50048*512*2
  u16*   h1b    = (u16*)(ws + 205389824L);         // 1024*512*2
  u16*   e_b    = (u16*)(ws + 206438400L);         // 1024*256*2
  u16*   wgb    = (u16*)(ws + 206962688L);         // 1024*256*2
  u16*   w2eb   = (u16*)(ws + 207486976L);         // 256*512*2
  u16*   wd1b   = (u16*)(ws + 207749120L);         // 512*256*2
  u16*   d1b    = (u16*)(ws + 208011264L);         // 1024*512*2
  u16*   hsb    = (u16*)(ws + 209059840L);         // 1024*256*2
  float* xw     = (float*)(ws + 209584128L);       // 1024*1024*4
  float* bws    = (float*)(ws + 213778432L);       // 1024*4
  u16*   upak   = (u16*)(ws + 213782528L);         // NSC*32768 u16 = 524288 B
  float* out    = (float*)d_out;
  float* P      = (float*)d_out;                   // split-K partials (67 MB) reuse d_out
  // self-validating mailbox in the tail of d_out (overwritten only by the
  // decoder GEMM, which runs after the scan): 2 parities x 256 u32
  u32*   hmail  = (u32*)((char*)d_out + 200000000L); // 2048 B

  hipMemsetAsync(hmail, 0, 2048, stream);          // tag 0 never matches st >= 1

  conv_x   <<<dim3(49,1024), 256, 0, stream>>>(x, xb);
  conv_w1  <<<dim3(49,512),  256, 0, stream>>>(enc_w1, w1b);
  conv_misc<<<2048, 256, 0, stream>>>(enc_w2, dec_w1, d_w_w, i_w_w, o_w_w, c_w_w, w2eb, wd1b, wgb);
  pack_bias<<<4, 256, 0, stream>>>(d_u_b, d_w_b, i_u_b, i_w_b, o_u_b, o_w_b, c_u_b, c_w_b, bws);
  pack_u   <<<NSC, 512, 0, stream>>>(d_u_w, i_u_w, o_u_w, c_u_w, upak);

  gemm_bt<0><<<dim3(8,4,32), 256, 0, stream>>>(xb, w1b, nullptr, P, nullptr, 50176, 50176, 512, 49, 0);
  reduce1<<<2048, 256, 0, stream>>>(P, enc_b1, h1b);
  gemm_bt<1><<<dim3(8,2,1), 256, 0, stream>>>(h1b, w2eb, enc_b2, nullptr, e_b, 512, 512, 256, 16, 0);
  gemm_bt<2><<<dim3(8,8,1), 256, 0, stream>>>(e_b, wgb, bws, xw, nullptr, 256, 256, 1024, 8, 0);
  // cooperative scan (blocks 0..7) + dec_w2 bf16 convert (blocks 8..196)
  scan_kernel<<<197, 512, 0, stream>>>((const u32x4*)upak, xw, hsb, dec_w2, w2db, hmail);
  gemm_bt<1><<<dim3(8,4,1), 256, 0, stream>>>(hsb, wd1b, dec_b1, nullptr, d1b, 256, 256, 512, 8, 0);
  gemm_bt<3><<<dim3(8,391,1), 256, 0, stream>>>(d1b, w2db, dec_b2, out, nullptr, 512, 512, 50000, 16, 50000);
}